// Round 5
// baseline (1473.266 us; speedup 1.0000x reference)
//
#include <hip/hip_runtime.h>
#include <hip/hip_bf16.h>
#include <math.h>

#define LN   2048
#define IDM  1024
#define NB   8
#define NEG_SLOPE 0.2f
#define LO_SCALE   4096.0f      // 2^12: keeps lo parts out of f16 denormal range
#define LO_INV     (1.0f/4096.0f)

typedef _Float16 f16x8 __attribute__((ext_vector_type(8)));
typedef float    f32x4 __attribute__((ext_vector_type(4)));

#define GLDS16(g, l) \
    __builtin_amdgcn_global_load_lds((const __attribute__((address_space(1))) void*)(g), \
                                     (__attribute__((address_space(3))) void*)(l), 16, 0, 0)

extern __shared__ char smem[];   // 128 KiB dynamic LDS: 2 bufs x (A 32K + B 32K)

// ---------------------------------------------------------------------------
// 256x256 tile, BK=64, 8 waves (2M x 4N), double-buffered LDS, counted vmcnt,
// st-swizzled LDS (byte ^= (row&7)<<4), setprio around MFMA, 2-segment K.
// Issue-early schedule: all 24 ds_reads -> lgkmcnt(0) -> barrier -> stage(t+2)
// (prefetch issued BEFORE the MFMA cluster: ~2 tiles of latency cover).
// Segment order: (A2,B2,K2) first (correction), then acc *= 2^-12, then (A1,B1,K1).
// A: [M][K] f16 rows (stride lda).  B: [N][K] f16 rows (stride ldb).
// EPI: 0 = split store hi|lo  (C f16 [M][2N]) ; 1 = split store lo|hi
//      2 = f32 store [M][N]
//      3 = f16 transposed per-2048-row-batch store: VT[b][N][2048]
//      4 = f16 store of (acc + E_f32[M][N])
//      5 = f32 store of leaky_relu(acc) + E_f32[row&2047][N]
// ---------------------------------------------------------------------------
template<int EPI>
__global__ __launch_bounds__(512, 2) void gemm256(
    const _Float16* __restrict__ A1, long long lda1, int K1,
    const _Float16* __restrict__ B1, long long ldb1,
    const _Float16* __restrict__ A2, long long lda2, int K2,
    const _Float16* __restrict__ B2, long long ldb2,
    const void* __restrict__ extraV, void* __restrict__ Cv,
    int M, int N,
    long long zsA, long long zsB, long long zsC, long long zsE)
{
    const int tid  = threadIdx.x;
    const int z    = blockIdx.z;
    const int m0   = blockIdx.y * 256, n0 = blockIdx.x * 256;
    const int lane = tid & 63;
    const int wid  = tid >> 6;
    const int wm   = wid >> 2;        // 0..1  (M half)
    const int wn   = wid & 3;         // 0..3  (N quarter)

    // staging constants: thread covers 16B at dest D = is*8192 + tid*16
    const int rA   = tid >> 3;                              // dest row 0..63 (+64*is)
    const int cF   = (((tid & 7) << 4) ^ ((rA & 7) << 4)) >> 1;  // pre-swizzled src col (f16)

    const int NT2 = K2 >> 6;
    const int NT  = NT2 + (K1 >> 6);

    const _Float16* A1z = A1 + (size_t)z * zsA;
    const _Float16* B1z = B1 + (size_t)z * zsB;
    const _Float16* A2z = (K2 > 0) ? A2 + (size_t)z * zsA : A1z;
    const _Float16* B2z = (K2 > 0) ? B2 + (size_t)z * zsB : B1z;

    auto stage = [&](int t) {
        const _Float16* As; const _Float16* Bs; long long la, lb; int kk;
        if (t < NT2) { As = A2z; Bs = B2z; la = lda2; lb = ldb2; kk = t << 6; }
        else         { As = A1z; Bs = B1z; la = lda1; lb = ldb1; kk = (t - NT2) << 6; }
        char* base = smem + (size_t)(t & 1) * 65536;
        #pragma unroll
        for (int is = 0; is < 4; ++is) {
            GLDS16(As + (size_t)(m0 + rA + is * 64) * la + kk + cF,
                   base + is * 8192 + tid * 16);
            GLDS16(Bs + (size_t)(n0 + rA + is * 64) * lb + kk + cF,
                   base + 32768 + is * 8192 + tid * 16);
        }
    };

    f32x4 acc[8][4] = {};

    stage(0);
    if (NT > 1) stage(1);

    #pragma unroll 1
    for (int t = 0; t < NT; ++t) {
        // tile t's loads retired in-order: <=8 outstanding leaves only t+1's.
        if (t < NT - 1) { asm volatile("s_waitcnt vmcnt(8)" ::: "memory"); }
        else            { asm volatile("s_waitcnt vmcnt(0)" ::: "memory"); }
        __builtin_amdgcn_s_barrier();            // group (t&1) visible to all waves
        __builtin_amdgcn_sched_barrier(0);

        const char* buf = smem + (size_t)(t & 1) * 65536;
        const int sw = (lane & 7) << 4;

        // --- all 24 fragment reads up front ---
        f16x8 aF[2][8], bF[2][4];
        #pragma unroll
        for (int ks = 0; ks < 2; ++ks) {
            const int kb = ks * 64 + ((lane >> 4) << 4);   // byte col in row
            #pragma unroll
            for (int mf = 0; mf < 8; ++mf) {
                const int row = wm * 128 + mf * 16 + (lane & 15);
                aF[ks][mf] = *(const f16x8*)(buf + ((row * 128 + kb) ^ sw));
            }
            #pragma unroll
            for (int nf = 0; nf < 4; ++nf) {
                const int row = wn * 64 + nf * 16 + (lane & 15);
                bF[ks][nf] = *(const f16x8*)(buf + 32768 + ((row * 128 + kb) ^ sw));
            }
        }
        asm volatile("s_waitcnt lgkmcnt(0)" ::: "memory");
        __builtin_amdgcn_sched_barrier(0);       // rule 18: no MFMA hoist above wait
        __builtin_amdgcn_s_barrier();            // all waves done reading group (t&1)

        // --- prefetch t+2 into the just-freed group, BEFORE the MFMA cluster ---
        if (t + 2 < NT) stage(t + 2);
        __builtin_amdgcn_sched_barrier(0);

        __builtin_amdgcn_s_setprio(1);
        #pragma unroll
        for (int ks = 0; ks < 2; ++ks)
            #pragma unroll
            for (int mf = 0; mf < 8; ++mf)
                #pragma unroll
                for (int nf = 0; nf < 4; ++nf)
                    acc[mf][nf] = __builtin_amdgcn_mfma_f32_16x16x32_f16(aF[ks][mf], bF[ks][nf], acc[mf][nf], 0, 0, 0);
        __builtin_amdgcn_s_setprio(0);

        if (t == NT2 - 1) {
            #pragma unroll
            for (int mf = 0; mf < 8; ++mf)
                #pragma unroll
                for (int nf = 0; nf < 4; ++nf)
                    acc[mf][nf] *= LO_INV;
        }
    }

    // C/D layout: col = lane&15, row = (lane>>4)*4 + reg
    const int colb = n0 + wn * 64 + (lane & 15);
    const int rowb = m0 + wm * 128 + ((lane >> 4) << 2);

    if (EPI == 0 || EPI == 1) {
        _Float16* C = (_Float16*)Cv + (size_t)z * zsC;
        const long long ldc = 2 * (long long)N;
        #pragma unroll
        for (int mf = 0; mf < 8; ++mf)
            #pragma unroll
            for (int nf = 0; nf < 4; ++nf)
                #pragma unroll
                for (int r = 0; r < 4; ++r) {
                    const int row = rowb + mf * 16 + r;
                    const int col = colb + nf * 16;
                    float v = acc[mf][nf][r];
                    _Float16 h = (_Float16)v;
                    _Float16 l = (_Float16)((v - (float)h) * LO_SCALE);
                    if (EPI == 0) {
                        C[(size_t)row * ldc + col]     = h;
                        C[(size_t)row * ldc + N + col] = l;
                    } else {
                        C[(size_t)row * ldc + col]     = l;
                        C[(size_t)row * ldc + N + col] = h;
                    }
                }
    } else if (EPI == 2) {
        float* C = (float*)Cv + (size_t)z * zsC;
        #pragma unroll
        for (int mf = 0; mf < 8; ++mf)
            #pragma unroll
            for (int nf = 0; nf < 4; ++nf)
                #pragma unroll
                for (int r = 0; r < 4; ++r)
                    C[(size_t)(rowb + mf * 16 + r) * N + (colb + nf * 16)] = acc[mf][nf][r];
    } else if (EPI == 3) {
        _Float16* C = (_Float16*)Cv;   // VT: [batch][N][2048]
        #pragma unroll
        for (int mf = 0; mf < 8; ++mf) {
            const int row = rowb + mf * 16;
            const int bt = row >> 11, ml = row & 2047;
            #pragma unroll
            for (int nf = 0; nf < 4; ++nf) {
                union { _Float16 h[4]; short4 s4; } u;
                #pragma unroll
                for (int r = 0; r < 4; ++r) u.h[r] = (_Float16)acc[mf][nf][r];
                *(short4*)&C[(size_t)bt * (size_t)IDM * 2048 + (size_t)(colb + nf * 16) * 2048 + ml] = u.s4;
            }
        }
    } else if (EPI == 4) {
        _Float16* C = (_Float16*)Cv + (size_t)z * zsC;
        const float* E = (const float*)extraV + (size_t)z * zsE;
        #pragma unroll
        for (int mf = 0; mf < 8; ++mf)
            #pragma unroll
            for (int nf = 0; nf < 4; ++nf)
                #pragma unroll
                for (int r = 0; r < 4; ++r) {
                    const size_t idx = (size_t)(rowb + mf * 16 + r) * N + (colb + nf * 16);
                    C[idx] = (_Float16)(acc[mf][nf][r] + E[idx]);
                }
    } else {  // EPI == 5
        float* C = (float*)Cv;
        const float* E = (const float*)extraV;
        #pragma unroll
        for (int mf = 0; mf < 8; ++mf)
            #pragma unroll
            for (int nf = 0; nf < 4; ++nf)
                #pragma unroll
                for (int r = 0; r < 4; ++r) {
                    const int row = rowb + mf * 16 + r;
                    const int col = colb + nf * 16;
                    float v = acc[mf][nf][r];
                    v = (v >= 0.f) ? v : NEG_SLOPE * v;
                    C[(size_t)row * N + col] = v + E[(size_t)(row & (LN - 1)) * N + col];
                }
    }
}

// ---------------------------------------------------------------------------
// i split: f32 [M][1024] -> f16 [M][2048]  (hi | lo*2^12)
__global__ __launch_bounds__(256) void split_i_k(
    const float* __restrict__ in, _Float16* __restrict__ out, long long n4)
{
    long long idx = (long long)blockIdx.x * 256 + threadIdx.x;
    if (idx >= n4) return;
    float4 v = ((const float4*)in)[idx];
    long long row = idx >> 8;
    int c4 = (int)(idx & 255) * 4;
    union { _Float16 h[4]; short4 s4; } hi, lo;
    float f0 = v.x; _Float16 h0 = (_Float16)f0; hi.h[0] = h0; lo.h[0] = (_Float16)((f0 - (float)h0) * LO_SCALE);
    float f1 = v.y; _Float16 h1 = (_Float16)f1; hi.h[1] = h1; lo.h[1] = (_Float16)((f1 - (float)h1) * LO_SCALE);
    float f2 = v.z; _Float16 h2 = (_Float16)f2; hi.h[2] = h2; lo.h[2] = (_Float16)((f2 - (float)h2) * LO_SCALE);
    float f3 = v.w; _Float16 h3 = (_Float16)f3; hi.h[3] = h3; lo.h[3] = (_Float16)((f3 - (float)h3) * LO_SCALE);
    *(short4*)&out[row * 2048 + c4]        = hi.s4;
    *(short4*)&out[row * 2048 + 1024 + c4] = lo.s4;
}

// weight transpose+split: in [K=1024][N=1024] f32 -> out [N][2048] (lo*2^12 | hi)
__global__ __launch_bounds__(256) void split_wT_k(
    const float* __restrict__ in, _Float16* __restrict__ out)
{
    __shared__ float t[32][33];
    const int bx = blockIdx.x * 32, by = blockIdx.y * 32;
    const int tx = threadIdx.x & 31, ty = threadIdx.x >> 5;
    #pragma unroll
    for (int i = 0; i < 32; i += 8)
        t[ty + i][tx] = in[(size_t)(by + ty + i) * 1024 + (bx + tx)];
    __syncthreads();
    #pragma unroll
    for (int i = 0; i < 32; i += 8) {
        float f = t[tx][ty + i];
        _Float16 h = (_Float16)f;
        _Float16 l = (_Float16)((f - (float)h) * LO_SCALE);
        const size_t n = bx + ty + i, k = by + tx;
        out[n * 2048 + k]        = l;
        out[n * 2048 + 1024 + k] = h;
    }
}

// plain transpose+convert: in [K=1024][N=1024] f32 -> out [N][1024] f16
__global__ __launch_bounds__(256) void transp_f32_f16(
    const float* __restrict__ in, _Float16* __restrict__ out)
{
    __shared__ float t[32][33];
    const int bx = blockIdx.x * 32, by = blockIdx.y * 32;
    const int tx = threadIdx.x & 31, ty = threadIdx.x >> 5;
    #pragma unroll
    for (int i = 0; i < 32; i += 8)
        t[ty + i][tx] = in[(size_t)(by + ty + i) * 1024 + (bx + tx)];
    __syncthreads();
    #pragma unroll
    for (int i = 0; i < 32; i += 8)
        out[(size_t)(bx + ty + i) * 1024 + (by + tx)] = (_Float16)t[tx][ty + i];
}

// in-place row softmax: S f32 row -> f16 written over the row's first half.
__global__ __launch_bounds__(256) void softmax_ip(float* __restrict__ S)
{
    const int tid = threadIdx.x;
    float* row = S + (size_t)blockIdx.y * LN * LN + (size_t)blockIdx.x * LN;

    float4 v0 = *(const float4*)&row[tid * 4];
    float4 v1 = *(const float4*)&row[1024 + tid * 4];

    float m = fmaxf(fmaxf(fmaxf(v0.x, v0.y), fmaxf(v0.z, v0.w)),
                    fmaxf(fmaxf(v1.x, v1.y), fmaxf(v1.z, v1.w)));
    #pragma unroll
    for (int off = 32; off > 0; off >>= 1) m = fmaxf(m, __shfl_xor(m, off));

    __shared__ float red[8];
    if ((tid & 63) == 0) red[tid >> 6] = m;
    __syncthreads();
    m = fmaxf(fmaxf(red[0], red[1]), fmaxf(red[2], red[3]));

    float e[8];
    e[0] = __expf(v0.x - m); e[1] = __expf(v0.y - m);
    e[2] = __expf(v0.z - m); e[3] = __expf(v0.w - m);
    e[4] = __expf(v1.x - m); e[5] = __expf(v1.y - m);
    e[6] = __expf(v1.z - m); e[7] = __expf(v1.w - m);
    float s = ((e[0] + e[1]) + (e[2] + e[3])) + ((e[4] + e[5]) + (e[6] + e[7]));
    #pragma unroll
    for (int off = 32; off > 0; off >>= 1) s += __shfl_xor(s, off);
    if ((tid & 63) == 0) red[4 + (tid >> 6)] = s;
    __syncthreads();
    s = (red[4] + red[5]) + (red[6] + red[7]);

    const float inv = 1.0f / s;
    _Float16* orow = (_Float16*)row;
    union { _Float16 h[4]; short4 s4; } a, b;
    a.h[0] = (_Float16)(e[0] * inv); a.h[1] = (_Float16)(e[1] * inv);
    a.h[2] = (_Float16)(e[2] * inv); a.h[3] = (_Float16)(e[3] * inv);
    b.h[0] = (_Float16)(e[4] * inv); b.h[1] = (_Float16)(e[5] * inv);
    b.h[2] = (_Float16)(e[6] * inv); b.h[3] = (_Float16)(e[7] * inv);
    *(short4*)&orow[tid * 4] = a.s4;
    *(short4*)&orow[1024 + tid * 4] = b.s4;
}

// ---------------------------------------------------------------------------
extern "C" void kernel_launch(void* const* d_in, const int* in_sizes, int n_in,
                              void* d_out, int out_size, void* d_ws, size_t ws_size,
                              hipStream_t stream)
{
    (void)in_sizes; (void)n_in; (void)out_size;
    const float* i_in  = (const float*)d_in[0];
    const float* k_w   = (const float*)d_in[1];
    const float* q_w   = (const float*)d_in[2];
    const float* v_w   = (const float*)d_in[3];
    const float* mlp_w = (const float*)d_in[4];
    const float* bias  = (const float*)d_in[5];
    float* out = (float*)d_out;

    (void)hipFuncSetAttribute((const void*)gemm256<0>, hipFuncAttributeMaxDynamicSharedMemorySize, 131072);
    (void)hipFuncSetAttribute((const void*)gemm256<1>, hipFuncAttributeMaxDynamicSharedMemorySize, 131072);
    (void)hipFuncSetAttribute((const void*)gemm256<2>, hipFuncAttributeMaxDynamicSharedMemorySize, 131072);
    (void)hipFuncSetAttribute((const void*)gemm256<3>, hipFuncAttributeMaxDynamicSharedMemorySize, 131072);
    (void)hipFuncSetAttribute((const void*)gemm256<4>, hipFuncAttributeMaxDynamicSharedMemorySize, 131072);
    (void)hipFuncSetAttribute((const void*)gemm256<5>, hipFuncAttributeMaxDynamicSharedMemorySize, 131072);

    char* ws = (char*)d_ws;
    const dim3 blk512(512);
    const dim3 blk256(256);
    const dim3 tgrid(32, 32);
    const size_t LDSB = 131072;

    const size_t MiB = 1ull << 20;
    const long long L2048 = 2048, L1024 = 1024, L4096 = 4096;

    if (ws_size >= 236 * MiB) {
        _Float16* Qcat  = (_Float16*)(ws);
        _Float16* Kcat  = (_Float16*)(ws + 64 * MiB);
        _Float16* VT    = (_Float16*)(ws + 128 * MiB);
        _Float16* qCatT = (_Float16*)(ws + 160 * MiB);
        _Float16* kCatT = (_Float16*)(ws + 164 * MiB);
        _Float16* vT    = (_Float16*)(ws + 168 * MiB);
        _Float16* mlpT  = (_Float16*)(ws + 170 * MiB);
        _Float16* iCat  = (_Float16*)(ws + 172 * MiB);
        float*    sc    = (float*)(ws + 172 * MiB);     // 4 batches x 16 MiB
        _Float16* ret   = Qcat;                          // [16384][1024], 32 MiB

        split_i_k<<<dim3(16384), blk256, 0, stream>>>(i_in, iCat, (long long)NB * LN * IDM / 4);
        split_wT_k<<<tgrid, blk256, 0, stream>>>(q_w, qCatT);
        split_wT_k<<<tgrid, blk256, 0, stream>>>(k_w, kCatT);
        transp_f32_f16<<<tgrid, blk256, 0, stream>>>(v_w, vT);
        transp_f32_f16<<<tgrid, blk256, 0, stream>>>(mlp_w, mlpT);

        const dim3 gproj(4, 64);
        gemm256<0><<<gproj, blk512, LDSB, stream>>>(
            iCat, L2048, 1024, qCatT + 1024, L2048,
            iCat, L2048, 2048, qCatT, L2048,
            nullptr, Qcat, NB * LN, 1024, 0, 0, 0, 0);
        gemm256<1><<<gproj, blk512, LDSB, stream>>>(
            iCat, L2048, 1024, kCatT + 1024, L2048,
            iCat, L2048, 2048, kCatT, L2048,
            nullptr, Kcat, NB * LN, 1024, 0, 0, 0, 0);
        gemm256<3><<<gproj, blk512, LDSB, stream>>>(
            iCat, L2048, 1024, vT, L1024,
            nullptr, 0, 0, nullptr, 0,
            nullptr, VT, NB * LN, 1024, 0, 0, 0, 0);
        // iCat now dead; sc aliases it.

        for (int c = 0; c < 2; ++c) {
            const size_t coff = (size_t)c * 4 * LN * 2048;
            gemm256<2><<<dim3(8, 8, 4), blk512, LDSB, stream>>>(
                Qcat + coff, L2048, 1024, Kcat + coff + 1024, L2048,
                Qcat + coff, L2048, 2048, Kcat + coff, L2048,
                nullptr, sc, LN, LN,
                (long long)LN * 2048, (long long)LN * 2048, (long long)LN * LN, 0);
            softmax_ip<<<dim3(LN, 4), blk256, 0, stream>>>(sc);
            gemm256<4><<<dim3(4, 8, 4), blk512, LDSB, stream>>>(
                (const _Float16*)sc, L4096, 2048, VT + (size_t)c * 4 * IDM * LN, L2048,
                nullptr, 0, 0, nullptr, 0,
                i_in + (size_t)c * 4 * LN * IDM, ret + (size_t)c * 4 * LN * IDM,
                LN, IDM,
                (long long)LN * LN * 2, (long long)IDM * LN, (long long)LN * IDM, (long long)LN * IDM);
        }
        gemm256<5><<<dim3(4, 64), blk512, LDSB, stream>>>(
            ret, L1024, 1024, mlpT, L1024,
            nullptr, 0, 0, nullptr, 0,
            bias, out, NB * LN, 1024, 0, 0, 0, 0);
    } else {
        // -------- small path (~60 MiB), per batch --------
        _Float16* qCatT = (_Float16*)(ws);
        _Float16* kCatT = (_Float16*)(ws + 4 * MiB);
        _Float16* vT    = (_Float16*)(ws + 8 * MiB);
        _Float16* mlpT  = (_Float16*)(ws + 10 * MiB);
        _Float16* iCat  = (_Float16*)(ws + 12 * MiB);
        _Float16* Qcat  = (_Float16*)(ws + 20 * MiB);
        _Float16* Kcat  = (_Float16*)(ws + 28 * MiB);
        _Float16* VTb   = (_Float16*)(ws + 36 * MiB);
        float*    sc    = (float*)(ws + 40 * MiB);
        _Float16* ret   = (_Float16*)(ws + 56 * MiB);

        split_wT_k<<<tgrid, blk256, 0, stream>>>(q_w, qCatT);
        split_wT_k<<<tgrid, blk256, 0, stream>>>(k_w, kCatT);
        transp_f32_f16<<<tgrid, blk256, 0, stream>>>(v_w, vT);
        transp_f32_f16<<<tgrid, blk256, 0, stream>>>(mlp_w, mlpT);

        for (int b = 0; b < NB; ++b) {
            const size_t boff = (size_t)b * LN * IDM;
            split_i_k<<<dim3(2048), blk256, 0, stream>>>(i_in + boff, iCat, (long long)LN * IDM / 4);
            gemm256<0><<<dim3(4, 8), blk512, LDSB, stream>>>(
                iCat, L2048, 1024, qCatT + 1024, L2048,
                iCat, L2048, 2048, qCatT, L2048,
                nullptr, Qcat, LN, 1024, 0, 0, 0, 0);
            gemm256<1><<<dim3(4, 8), blk512, LDSB, stream>>>(
                iCat, L2048, 1024, kCatT + 1024, L2048,
                iCat, L2048, 2048, kCatT, L2048,
                nullptr, Kcat, LN, 1024, 0, 0, 0, 0);
            gemm256<3><<<dim3(4, 8), blk512, LDSB, stream>>>(
                iCat, L2048, 1024, vT, L1024,
                nullptr, 0, 0, nullptr, 0,
                nullptr, VTb, LN, 1024, 0, 0, 0, 0);
            gemm256<2><<<dim3(8, 8), blk512, LDSB, stream>>>(
                Qcat, L2048, 1024, Kcat + 1024, L2048,
                Qcat, L2048, 2048, Kcat, L2048,
                nullptr, sc, LN, LN, 0, 0, 0, 0);
            softmax_ip<<<dim3(LN, 1), blk256, 0, stream>>>(sc);
            gemm256<4><<<dim3(4, 8), blk512, LDSB, stream>>>(
                (const _Float16*)sc, L4096, 2048, VTb, L2048,
                nullptr, 0, 0, nullptr, 0,
                i_in + boff, ret, LN, IDM, 0, 0, 0, 0);
            gemm256<5><<<dim3(4, 8), blk512, LDSB, stream>>>(
                ret, L1024, 1024, mlpT, L1024,
                nullptr, 0, 0, nullptr, 0,
                bias, out + boff, LN, 1024, 0, 0, 0, 0);
        }
    }
}

// Round 6
// 780.317 us; speedup vs baseline: 1.8880x; 1.8880x over previous
//
#include <hip/hip_runtime.h>
#include <hip/hip_bf16.h>
#include <math.h>

#define LN   2048
#define IDM  1024
#define NB   8
#define NEG_SLOPE 0.2f
#define LO_SCALE   4096.0f      // 2^12: keeps lo parts out of f16 denormal range
#define LO_INV     (1.0f/4096.0f)

typedef _Float16 f16x8 __attribute__((ext_vector_type(8)));
typedef float    f32x4 __attribute__((ext_vector_type(4)));

#define GLDS16(g, l) \
    __builtin_amdgcn_global_load_lds((const __attribute__((address_space(1))) void*)(g), \
                                     (__attribute__((address_space(3))) void*)(l), 16, 0, 0)

extern __shared__ char smem[];   // 128 KiB: 4 buffers x (A 16K + B 16K)

// ---------------------------------------------------------------------------
// 256x256 tile, BK=32, 8 waves (2M x 4N), 4-deep LDS pipeline:
//   iter t: stage(t+3) -> 12 ds_read -> 32 MFMA -> counted vmcnt -> barrier.
// One barrier + one counted vmcnt per K-tile; loads span 3 tiles (never drain
// vmcnt to 0 mid-loop).  LDS slot-swizzle: slot ^= row&3 (inverse-applied on
// the global source; linear global_load_lds dest; swizzled ds_read).
// 2-segment K: (A2,B2,K2) correction first, then acc *= 2^-12, then (A1,B1,K1).
// A: [M][K] f16 rows (stride lda).  B: [N][K] f16 rows (stride ldb).
// EPI: 0 = split store hi|lo  (C f16 [M][2N]) ; 1 = split store lo|hi
//      2 = f32 store [M][N]
//      3 = f16 transposed per-2048-row-batch store: VT[b][N][2048]
//      4 = f16 store of (acc + E_f32[M][N])
//      5 = f32 store of leaky_relu(acc) + E_f32[row&2047][N]
// ---------------------------------------------------------------------------
template<int EPI>
__global__ __launch_bounds__(512, 2) void gemm256(
    const _Float16* __restrict__ A1, long long lda1, int K1,
    const _Float16* __restrict__ B1, long long ldb1,
    const _Float16* __restrict__ A2, long long lda2, int K2,
    const _Float16* __restrict__ B2, long long ldb2,
    const void* __restrict__ extraV, void* __restrict__ Cv,
    int M, int N,
    long long zsA, long long zsB, long long zsC, long long zsE)
{
    const int tid  = threadIdx.x;

    // bijective XCD swizzle (all launch grids have nwg % 8 == 0)
    const unsigned nx = gridDim.x, ny = gridDim.y;
    const unsigned lid = blockIdx.x + nx * (blockIdx.y + ny * blockIdx.z);
    const unsigned cpx = (nx * ny * gridDim.z) >> 3;
    const unsigned swzid = (lid & 7) * cpx + (lid >> 3);
    const unsigned bx = swzid % nx, rest = swzid / nx;
    const unsigned by = rest % ny;
    const int z  = (int)(rest / ny);
    const int m0 = (int)by * 256, n0 = (int)bx * 256;

    const int lane = tid & 63;
    const int wid  = tid >> 6;
    const int wm   = wid >> 2;        // 0..1  (M half)
    const int wn   = wid & 3;         // 0..3  (N quarter)

    // staging: dest row = is*128 + (tid>>2), dest slot = tid&3 (linear dest)
    const int srow = tid >> 2;
    const int sx   = ((tid & 3) ^ (srow & 3)) << 3;   // inverse-swizzled src col (f16)

    const int NT2 = K2 >> 5;
    const int NT  = NT2 + (K1 >> 5);

    const _Float16* A1z = A1 + (size_t)z * zsA;
    const _Float16* B1z = B1 + (size_t)z * zsB;
    const _Float16* A2z = (K2 > 0) ? A2 + (size_t)z * zsA : A1z;
    const _Float16* B2z = (K2 > 0) ? B2 + (size_t)z * zsB : B1z;

    auto stage = [&](int t) {
        const _Float16* As; const _Float16* Bs; long long la, lb; int kk;
        if (t < NT2) { As = A2z; Bs = B2z; la = lda2; lb = ldb2; kk = t << 5; }
        else         { As = A1z; Bs = B1z; la = lda1; lb = ldb1; kk = (t - NT2) << 5; }
        char* base = smem + (size_t)(t & 3) * 32768;
        #pragma unroll
        for (int is = 0; is < 2; ++is) {
            GLDS16(As + (size_t)(m0 + is * 128 + srow) * la + kk + sx,
                   base + is * 8192 + tid * 16);
            GLDS16(Bs + (size_t)(n0 + is * 128 + srow) * lb + kk + sx,
                   base + 16384 + is * 8192 + tid * 16);
        }
    };

    f32x4 acc[8][4] = {};

    stage(0); stage(1); stage(2);
    asm volatile("s_waitcnt vmcnt(8)" ::: "memory");   // tile 0 landed
    __builtin_amdgcn_s_barrier();
    __builtin_amdgcn_sched_barrier(0);

    const int fr  = lane & 15;
    const int ks4 = (((lane >> 4) ^ (lane & 3)) << 4);  // swizzled byte slot

    #pragma unroll 1
    for (int t = 0; t < NT; ++t) {
        if (t + 3 < NT) stage(t + 3);   // buffer (t-1)&3: freed by prev barrier

        const char* buf = smem + (size_t)(t & 3) * 32768;
        f16x8 aF[8], bF[4];
        #pragma unroll
        for (int mf = 0; mf < 8; ++mf)
            aF[mf] = *(const f16x8*)(buf + (wm * 128 + mf * 16 + fr) * 64 + ks4);
        #pragma unroll
        for (int nf = 0; nf < 4; ++nf)
            bF[nf] = *(const f16x8*)(buf + 16384 + (wn * 64 + nf * 16 + fr) * 64 + ks4);

        __builtin_amdgcn_s_setprio(1);
        #pragma unroll
        for (int mf = 0; mf < 8; ++mf)
            #pragma unroll
            for (int nf = 0; nf < 4; ++nf)
                acc[mf][nf] = __builtin_amdgcn_mfma_f32_16x16x32_f16(aF[mf], bF[nf], acc[mf][nf], 0, 0, 0);
        __builtin_amdgcn_s_setprio(0);

        if (t == NT2 - 1) {
            #pragma unroll
            for (int mf = 0; mf < 8; ++mf)
                #pragma unroll
                for (int nf = 0; nf < 4; ++nf)
                    acc[mf][nf] *= LO_INV;
        }

        if (t + 1 < NT) {
            __builtin_amdgcn_sched_barrier(0);
            const int rem = NT - 2 - t;   // tiles staged after t+1
            if (rem >= 2)      asm volatile("s_waitcnt vmcnt(8)" ::: "memory");
            else if (rem == 1) asm volatile("s_waitcnt vmcnt(4)" ::: "memory");
            else               asm volatile("s_waitcnt vmcnt(0)" ::: "memory");
            __builtin_amdgcn_s_barrier();
            __builtin_amdgcn_sched_barrier(0);
        }
    }

    // C/D layout: col = lane&15, row = (lane>>4)*4 + reg
    const int colb = n0 + wn * 64 + (lane & 15);
    const int rowb = m0 + wm * 128 + ((lane >> 4) << 2);

    if (EPI == 0 || EPI == 1) {
        _Float16* C = (_Float16*)Cv + (size_t)z * zsC;
        const long long ldc = 2 * (long long)N;
        #pragma unroll
        for (int mf = 0; mf < 8; ++mf)
            #pragma unroll
            for (int nf = 0; nf < 4; ++nf)
                #pragma unroll
                for (int r = 0; r < 4; ++r) {
                    const int row = rowb + mf * 16 + r;
                    const int col = colb + nf * 16;
                    float v = acc[mf][nf][r];
                    _Float16 h = (_Float16)v;
                    _Float16 l = (_Float16)((v - (float)h) * LO_SCALE);
                    if (EPI == 0) {
                        C[(size_t)row * ldc + col]     = h;
                        C[(size_t)row * ldc + N + col] = l;
                    } else {
                        C[(size_t)row * ldc + col]     = l;
                        C[(size_t)row * ldc + N + col] = h;
                    }
                }
    } else if (EPI == 2) {
        float* C = (float*)Cv + (size_t)z * zsC;
        #pragma unroll
        for (int mf = 0; mf < 8; ++mf)
            #pragma unroll
            for (int nf = 0; nf < 4; ++nf)
                #pragma unroll
                for (int r = 0; r < 4; ++r)
                    C[(size_t)(rowb + mf * 16 + r) * N + (colb + nf * 16)] = acc[mf][nf][r];
    } else if (EPI == 3) {
        _Float16* C = (_Float16*)Cv;   // VT: [batch][N][2048]
        #pragma unroll
        for (int mf = 0; mf < 8; ++mf) {
            const int row = rowb + mf * 16;
            const int bt = row >> 11, ml = row & 2047;
            #pragma unroll
            for (int nf = 0; nf < 4; ++nf) {
                union { _Float16 h[4]; short4 s4; } u;
                #pragma unroll
                for (int r = 0; r < 4; ++r) u.h[r] = (_Float16)acc[mf][nf][r];
                *(short4*)&C[(size_t)bt * (size_t)IDM * 2048 + (size_t)(colb + nf * 16) * 2048 + ml] = u.s4;
            }
        }
    } else if (EPI == 4) {
        _Float16* C = (_Float16*)Cv + (size_t)z * zsC;
        const float* E = (const float*)extraV + (size_t)z * zsE;
        #pragma unroll
        for (int mf = 0; mf < 8; ++mf)
            #pragma unroll
            for (int nf = 0; nf < 4; ++nf)
                #pragma unroll
                for (int r = 0; r < 4; ++r) {
                    const size_t idx = (size_t)(rowb + mf * 16 + r) * N + (colb + nf * 16);
                    C[idx] = (_Float16)(acc[mf][nf][r] + E[idx]);
                }
    } else {  // EPI == 5
        float* C = (float*)Cv;
        const float* E = (const float*)extraV;
        #pragma unroll
        for (int mf = 0; mf < 8; ++mf)
            #pragma unroll
            for (int nf = 0; nf < 4; ++nf)
                #pragma unroll
                for (int r = 0; r < 4; ++r) {
                    const int row = rowb + mf * 16 + r;
                    const int col = colb + nf * 16;
                    float v = acc[mf][nf][r];
                    v = (v >= 0.f) ? v : NEG_SLOPE * v;
                    C[(size_t)row * N + col] = v + E[(size_t)(row & (LN - 1)) * N + col];
                }
    }
}

// ---------------------------------------------------------------------------
// i split: f32 [M][1024] -> f16 [M][2048]  (hi | lo*2^12)
__global__ __launch_bounds__(256) void split_i_k(
    const float* __restrict__ in, _Float16* __restrict__ out, long long n4)
{
    long long idx = (long long)blockIdx.x * 256 + threadIdx.x;
    if (idx >= n4) return;
    float4 v = ((const float4*)in)[idx];
    long long row = idx >> 8;
    int c4 = (int)(idx & 255) * 4;
    union { _Float16 h[4]; short4 s4; } hi, lo;
    float f0 = v.x; _Float16 h0 = (_Float16)f0; hi.h[0] = h0; lo.h[0] = (_Float16)((f0 - (float)h0) * LO_SCALE);
    float f1 = v.y; _Float16 h1 = (_Float16)f1; hi.h[1] = h1; lo.h[1] = (_Float16)((f1 - (float)h1) * LO_SCALE);
    float f2 = v.z; _Float16 h2 = (_Float16)f2; hi.h[2] = h2; lo.h[2] = (_Float16)((f2 - (float)h2) * LO_SCALE);
    float f3 = v.w; _Float16 h3 = (_Float16)f3; hi.h[3] = h3; lo.h[3] = (_Float16)((f3 - (float)h3) * LO_SCALE);
    *(short4*)&out[row * 2048 + c4]        = hi.s4;
    *(short4*)&out[row * 2048 + 1024 + c4] = lo.s4;
}

// weight transpose+split: in [K=1024][N=1024] f32 -> out [N][2048] (lo*2^12 | hi)
__global__ __launch_bounds__(256) void split_wT_k(
    const float* __restrict__ in, _Float16* __restrict__ out)
{
    __shared__ float t[32][33];
    const int bx = blockIdx.x * 32, by = blockIdx.y * 32;
    const int tx = threadIdx.x & 31, ty = threadIdx.x >> 5;
    #pragma unroll
    for (int i = 0; i < 32; i += 8)
        t[ty + i][tx] = in[(size_t)(by + ty + i) * 1024 + (bx + tx)];
    __syncthreads();
    #pragma unroll
    for (int i = 0; i < 32; i += 8) {
        float f = t[tx][ty + i];
        _Float16 h = (_Float16)f;
        _Float16 l = (_Float16)((f - (float)h) * LO_SCALE);
        const size_t n = bx + ty + i, k = by + tx;
        out[n * 2048 + k]        = l;
        out[n * 2048 + 1024 + k] = h;
    }
}

// plain transpose+convert: in [K=1024][N=1024] f32 -> out [N][1024] f16
__global__ __launch_bounds__(256) void transp_f32_f16(
    const float* __restrict__ in, _Float16* __restrict__ out)
{
    __shared__ float t[32][33];
    const int bx = blockIdx.x * 32, by = blockIdx.y * 32;
    const int tx = threadIdx.x & 31, ty = threadIdx.x >> 5;
    #pragma unroll
    for (int i = 0; i < 32; i += 8)
        t[ty + i][tx] = in[(size_t)(by + ty + i) * 1024 + (bx + tx)];
    __syncthreads();
    #pragma unroll
    for (int i = 0; i < 32; i += 8)
        out[(size_t)(bx + ty + i) * 1024 + (by + tx)] = (_Float16)t[tx][ty + i];
}

// in-place row softmax: S f32 row -> f16 written over the row's first half.
__global__ __launch_bounds__(256) void softmax_ip(float* __restrict__ S)
{
    const int tid = threadIdx.x;
    float* row = S + (size_t)blockIdx.y * LN * LN + (size_t)blockIdx.x * LN;

    float4 v0 = *(const float4*)&row[tid * 4];
    float4 v1 = *(const float4*)&row[1024 + tid * 4];

    float m = fmaxf(fmaxf(fmaxf(v0.x, v0.y), fmaxf(v0.z, v0.w)),
                    fmaxf(fmaxf(v1.x, v1.y), fmaxf(v1.z, v1.w)));
    #pragma unroll
    for (int off = 32; off > 0; off >>= 1) m = fmaxf(m, __shfl_xor(m, off));

    __shared__ float red[8];
    if ((tid & 63) == 0) red[tid >> 6] = m;
    __syncthreads();
    m = fmaxf(fmaxf(red[0], red[1]), fmaxf(red[2], red[3]));

    float e[8];
    e[0] = __expf(v0.x - m); e[1] = __expf(v0.y - m);
    e[2] = __expf(v0.z - m); e[3] = __expf(v0.w - m);
    e[4] = __expf(v1.x - m); e[5] = __expf(v1.y - m);
    e[6] = __expf(v1.z - m); e[7] = __expf(v1.w - m);
    float s = ((e[0] + e[1]) + (e[2] + e[3])) + ((e[4] + e[5]) + (e[6] + e[7]));
    #pragma unroll
    for (int off = 32; off > 0; off >>= 1) s += __shfl_xor(s, off);
    if ((tid & 63) == 0) red[4 + (tid >> 6)] = s;
    __syncthreads();
    s = (red[4] + red[5]) + (red[6] + red[7]);

    const float inv = 1.0f / s;
    _Float16* orow = (_Float16*)row;
    union { _Float16 h[4]; short4 s4; } a, b;
    a.h[0] = (_Float16)(e[0] * inv); a.h[1] = (_Float16)(e[1] * inv);
    a.h[2] = (_Float16)(e[2] * inv); a.h[3] = (_Float16)(e[3] * inv);
    b.h[0] = (_Float16)(e[4] * inv); b.h[1] = (_Float16)(e[5] * inv);
    b.h[2] = (_Float16)(e[6] * inv); b.h[3] = (_Float16)(e[7] * inv);
    *(short4*)&orow[tid * 4] = a.s4;
    *(short4*)&orow[1024 + tid * 4] = b.s4;
}

// ---------------------------------------------------------------------------
extern "C" void kernel_launch(void* const* d_in, const int* in_sizes, int n_in,
                              void* d_out, int out_size, void* d_ws, size_t ws_size,
                              hipStream_t stream)
{
    (void)in_sizes; (void)n_in; (void)out_size;
    const float* i_in  = (const float*)d_in[0];
    const float* k_w   = (const float*)d_in[1];
    const float* q_w   = (const float*)d_in[2];
    const float* v_w   = (const float*)d_in[3];
    const float* mlp_w = (const float*)d_in[4];
    const float* bias  = (const float*)d_in[5];
    float* out = (float*)d_out;

    (void)hipFuncSetAttribute((const void*)gemm256<0>, hipFuncAttributeMaxDynamicSharedMemorySize, 131072);
    (void)hipFuncSetAttribute((const void*)gemm256<1>, hipFuncAttributeMaxDynamicSharedMemorySize, 131072);
    (void)hipFuncSetAttribute((const void*)gemm256<2>, hipFuncAttributeMaxDynamicSharedMemorySize, 131072);
    (void)hipFuncSetAttribute((const void*)gemm256<3>, hipFuncAttributeMaxDynamicSharedMemorySize, 131072);
    (void)hipFuncSetAttribute((const void*)gemm256<4>, hipFuncAttributeMaxDynamicSharedMemorySize, 131072);
    (void)hipFuncSetAttribute((const void*)gemm256<5>, hipFuncAttributeMaxDynamicSharedMemorySize, 131072);

    char* ws = (char*)d_ws;
    const dim3 blk512(512);
    const dim3 blk256(256);
    const dim3 tgrid(32, 32);
    const size_t LDSB = 131072;

    const size_t MiB = 1ull << 20;
    const long long L2048 = 2048, L1024 = 1024, L4096 = 4096;

    if (ws_size >= 236 * MiB) {
        _Float16* Qcat  = (_Float16*)(ws);
        _Float16* Kcat  = (_Float16*)(ws + 64 * MiB);
        _Float16* VT    = (_Float16*)(ws + 128 * MiB);
        _Float16* qCatT = (_Float16*)(ws + 160 * MiB);
        _Float16* kCatT = (_Float16*)(ws + 164 * MiB);
        _Float16* vT    = (_Float16*)(ws + 168 * MiB);
        _Float16* mlpT  = (_Float16*)(ws + 170 * MiB);
        _Float16* iCat  = (_Float16*)(ws + 172 * MiB);
        float*    sc    = (float*)(ws + 172 * MiB);     // 4 batches x 16 MiB
        _Float16* ret   = Qcat;                          // [16384][1024], 32 MiB

        split_i_k<<<dim3(16384), blk256, 0, stream>>>(i_in, iCat, (long long)NB * LN * IDM / 4);
        split_wT_k<<<tgrid, blk256, 0, stream>>>(q_w, qCatT);
        split_wT_k<<<tgrid, blk256, 0, stream>>>(k_w, kCatT);
        transp_f32_f16<<<tgrid, blk256, 0, stream>>>(v_w, vT);
        transp_f32_f16<<<tgrid, blk256, 0, stream>>>(mlp_w, mlpT);

        const dim3 gproj(4, 64);
        gemm256<0><<<gproj, blk512, LDSB, stream>>>(
            iCat, L2048, 1024, qCatT + 1024, L2048,
            iCat, L2048, 2048, qCatT, L2048,
            nullptr, Qcat, NB * LN, 1024, 0, 0, 0, 0);
        gemm256<1><<<gproj, blk512, LDSB, stream>>>(
            iCat, L2048, 1024, kCatT + 1024, L2048,
            iCat, L2048, 2048, kCatT, L2048,
            nullptr, Kcat, NB * LN, 1024, 0, 0, 0, 0);
        gemm256<3><<<gproj, blk512, LDSB, stream>>>(
            iCat, L2048, 1024, vT, L1024,
            nullptr, 0, 0, nullptr, 0,
            nullptr, VT, NB * LN, 1024, 0, 0, 0, 0);
        // iCat now dead; sc aliases it.

        for (int c = 0; c < 2; ++c) {
            const size_t coff = (size_t)c * 4 * LN * 2048;
            gemm256<2><<<dim3(8, 8, 4), blk512, LDSB, stream>>>(
                Qcat + coff, L2048, 1024, Kcat + coff + 1024, L2048,
                Qcat + coff, L2048, 2048, Kcat + coff, L2048,
                nullptr, sc, LN, LN,
                (long long)LN * 2048, (long long)LN * 2048, (long long)LN * LN, 0);
            softmax_ip<<<dim3(LN, 4), blk256, 0, stream>>>(sc);
            gemm256<4><<<dim3(4, 8, 4), blk512, LDSB, stream>>>(
                (const _Float16*)sc, L4096, 2048, VT + (size_t)c * 4 * IDM * LN, L2048,
                nullptr, 0, 0, nullptr, 0,
                i_in + (size_t)c * 4 * LN * IDM, ret + (size_t)c * 4 * LN * IDM,
                LN, IDM,
                (long long)LN * LN * 2, (long long)IDM * LN, (long long)LN * IDM, (long long)LN * IDM);
        }
        gemm256<5><<<dim3(4, 64), blk512, LDSB, stream>>>(
            ret, L1024, 1024, mlpT, L1024,
            nullptr, 0, 0, nullptr, 0,
            bias, out, NB * LN, 1024, 0, 0, 0, 0);
    } else {
        // -------- small path (~60 MiB), per batch --------
        _Float16* qCatT = (_Float16*)(ws);
        _Float16* kCatT = (_Float16*)(ws + 4 * MiB);
        _Float16* vT    = (_Float16*)(ws + 8 * MiB);
        _Float16* mlpT  = (_Float16*)(ws + 10 * MiB);
        _Float16* iCat  = (_Float16*)(ws + 12 * MiB);
        _Float16* Qcat  = (_Float16*)(ws + 20 * MiB);
        _Float16* Kcat  = (_Float16*)(ws + 28 * MiB);
        _Float16* VTb   = (_Float16*)(ws + 36 * MiB);
        float*    sc    = (float*)(ws + 40 * MiB);
        _Float16* ret   = (_Float16*)(ws + 56 * MiB);

        split_wT_k<<<tgrid, blk256, 0, stream>>>(q_w, qCatT);
        split_wT_k<<<tgrid, blk256, 0, stream>>>(k_w, kCatT);
        transp_f32_f16<<<tgrid, blk256, 0, stream>>>(v_w, vT);
        transp_f32_f16<<<tgrid, blk256, 0, stream>>>(mlp_w, mlpT);

        for (int b = 0; b < NB; ++b) {
            const size_t boff = (size_t)b * LN * IDM;
            split_i_k<<<dim3(2048), blk256, 0, stream>>>(i_in + boff, iCat, (long long)LN * IDM / 4);
            gemm256<0><<<dim3(4, 8), blk512, LDSB, stream>>>(
                iCat, L2048, 1024, qCatT + 1024, L2048,
                iCat, L2048, 2048, qCatT, L2048,
                nullptr, Qcat, LN, 1024, 0, 0, 0, 0);
            gemm256<1><<<dim3(4, 8), blk512, LDSB, stream>>>(
                iCat, L2048, 1024, kCatT + 1024, L2048,
                iCat, L2048, 2048, kCatT, L2048,
                nullptr, Kcat, LN, 1024, 0, 0, 0, 0);
            gemm256<3><<<dim3(4, 8), blk512, LDSB, stream>>>(
                iCat, L2048, 1024, vT, L1024,
                nullptr, 0, 0, nullptr, 0,
                nullptr, VTb, LN, 1024, 0, 0, 0, 0);
            gemm256<2><<<dim3(8, 8), blk512, LDSB, stream>>>(
                Qcat, L2048, 1024, Kcat + 1024, L2048,
                Qcat, L2048, 2048, Kcat, L2048,
                nullptr, sc, LN, LN, 0, 0, 0, 0);
            softmax_ip<<<dim3(LN, 1), blk256, 0, stream>>>(sc);
            gemm256<4><<<dim3(4, 8), blk512, LDSB, stream>>>(
                (const _Float16*)sc, L4096, 2048, VTb, L2048,
                nullptr, 0, 0, nullptr, 0,
                i_in + boff, ret, LN, IDM, 0, 0, 0, 0);
            gemm256<5><<<dim3(4, 8), blk512, LDSB, stream>>>(
                ret, L1024, 1024, mlpT, L1024,
                nullptr, 0, 0, nullptr, 0,
                bias, out + boff, LN, 1024, 0, 0, 0, 0);
        }
    }
}

// Round 7
// 746.861 us; speedup vs baseline: 1.9726x; 1.0448x over previous
//
#include <hip/hip_runtime.h>
#include <hip/hip_bf16.h>
#include <math.h>

#define LN   2048
#define IDM  1024
#define NB   8
#define NEG_SLOPE 0.2f
#define LO_SCALE   4096.0f      // 2^12: keeps lo parts out of f16 denormal range
#define LO_INV     (1.0f/4096.0f)

typedef _Float16 f16x8 __attribute__((ext_vector_type(8)));
typedef float    f32x4 __attribute__((ext_vector_type(4)));

#define GLDS16(g, l) \
    __builtin_amdgcn_global_load_lds((const __attribute__((address_space(1))) void*)(g), \
                                     (__attribute__((address_space(3))) void*)(l), 16, 0, 0)

extern __shared__ char smem[];   // 128 KiB: 4 buffers x (A 16K + B 16K)

// ---------------------------------------------------------------------------
// 256x256 tile, BK=32, 8 waves (2M x 4N), 4-deep LDS pipeline:
//   iter t: stage(t+3) -> 12 ds_read -> 32 MFMA -> counted vmcnt -> barrier.
// One barrier + one counted vmcnt per K-tile; loads span 3 tiles.
// LDS slot-swizzle key = (row>>1)&3  (NOT row&3: with 64-B rows the bank
// group is 4*(row&1)+slot mod 8, so the key must advance once per TWO rows
// to cover all 8 groups; residual 2-way alias is free).  Inverse-applied on
// the global source; linear global_load_lds dest; same key on ds_read.
// 2-segment K: (A2,B2,K2) correction first, then acc *= 2^-12, then (A1,B1,K1).
// A: [M][K] f16 rows (stride lda).  B: [N][K] f16 rows (stride ldb).
// EPI: 0 = split store hi|lo  (C f16 [M][2N]) ; 1 = split store lo|hi
//      2 = f32 store [M][N]
//      3 = f16 transposed per-2048-row-batch store: VT[b][N][2048]
//      4 = f16 store of (acc + E_f32[M][N])
//      5 = f32 store of leaky_relu(acc) + E_f32[row&2047][N]
//      6 = fused QK-proj store (N=2048): col<1024 -> Cv=Qcat hi|lo,
//          col>=1024 -> extraV=Kcat lo|hi (both [M][2048])
// ---------------------------------------------------------------------------
template<int EPI>
__global__ __launch_bounds__(512, 2) void gemm256(
    const _Float16* __restrict__ A1, long long lda1, int K1,
    const _Float16* __restrict__ B1, long long ldb1,
    const _Float16* __restrict__ A2, long long lda2, int K2,
    const _Float16* __restrict__ B2, long long ldb2,
    const void* __restrict__ extraV, void* __restrict__ Cv,
    int M, int N,
    long long zsA, long long zsB, long long zsC, long long zsE)
{
    const int tid  = threadIdx.x;

    // bijective XCD swizzle (all launch grids have nwg % 8 == 0)
    const unsigned nx = gridDim.x, ny = gridDim.y;
    const unsigned lid = blockIdx.x + nx * (blockIdx.y + ny * blockIdx.z);
    const unsigned cpx = (nx * ny * gridDim.z) >> 3;
    const unsigned swzid = (lid & 7) * cpx + (lid >> 3);
    const unsigned bx = swzid % nx, rest = swzid / nx;
    const unsigned by = rest % ny;
    const int z  = (int)(rest / ny);
    const int m0 = (int)by * 256, n0 = (int)bx * 256;

    const int lane = tid & 63;
    const int wid  = tid >> 6;
    const int wm   = wid >> 2;        // 0..1  (M half)
    const int wn   = wid & 3;         // 0..3  (N quarter)

    // staging: dest row = is*128 + (tid>>2), dest slot = tid&3 (linear dest)
    // source col inverse-swizzled with key (destrow>>1)&3 = (tid>>3)&3
    const int srow = tid >> 2;
    const int sx   = ((tid & 3) ^ ((tid >> 3) & 3)) << 3;   // f16 units

    const int NT2 = K2 >> 5;
    const int NT  = NT2 + (K1 >> 5);

    const _Float16* A1z = A1 + (size_t)z * zsA;
    const _Float16* B1z = B1 + (size_t)z * zsB;
    const _Float16* A2z = (K2 > 0) ? A2 + (size_t)z * zsA : A1z;
    const _Float16* B2z = (K2 > 0) ? B2 + (size_t)z * zsB : B1z;

    auto stage = [&](int t) {
        const _Float16* As; const _Float16* Bs; long long la, lb; int kk;
        if (t < NT2) { As = A2z; Bs = B2z; la = lda2; lb = ldb2; kk = t << 5; }
        else         { As = A1z; Bs = B1z; la = lda1; lb = ldb1; kk = (t - NT2) << 5; }
        char* base = smem + (size_t)(t & 3) * 32768;
        #pragma unroll
        for (int is = 0; is < 2; ++is) {
            GLDS16(As + (size_t)(m0 + is * 128 + srow) * la + kk + sx,
                   base + is * 8192 + tid * 16);
            GLDS16(Bs + (size_t)(n0 + is * 128 + srow) * lb + kk + sx,
                   base + 16384 + is * 8192 + tid * 16);
        }
    };

    f32x4 acc[8][4] = {};

    stage(0); stage(1); stage(2);
    asm volatile("s_waitcnt vmcnt(8)" ::: "memory");   // tile 0 landed
    __builtin_amdgcn_s_barrier();
    __builtin_amdgcn_sched_barrier(0);

    const int fr  = lane & 15;
    const int ks4 = (((lane >> 4) ^ ((lane >> 1) & 3)) << 4);  // swizzled byte slot

    #pragma unroll 1
    for (int t = 0; t < NT; ++t) {
        if (t + 3 < NT) stage(t + 3);   // buffer (t-1)&3: freed by prev barrier

        const char* buf = smem + (size_t)(t & 3) * 32768;
        f16x8 aF[8], bF[4];
        #pragma unroll
        for (int mf = 0; mf < 8; ++mf)
            aF[mf] = *(const f16x8*)(buf + (wm * 128 + mf * 16 + fr) * 64 + ks4);
        #pragma unroll
        for (int nf = 0; nf < 4; ++nf)
            bF[nf] = *(const f16x8*)(buf + 16384 + (wn * 64 + nf * 16 + fr) * 64 + ks4);

        __builtin_amdgcn_s_setprio(1);
        #pragma unroll
        for (int mf = 0; mf < 8; ++mf)
            #pragma unroll
            for (int nf = 0; nf < 4; ++nf)
                acc[mf][nf] = __builtin_amdgcn_mfma_f32_16x16x32_f16(aF[mf], bF[nf], acc[mf][nf], 0, 0, 0);
        __builtin_amdgcn_s_setprio(0);

        if (t == NT2 - 1) {
            #pragma unroll
            for (int mf = 0; mf < 8; ++mf)
                #pragma unroll
                for (int nf = 0; nf < 4; ++nf)
                    acc[mf][nf] *= LO_INV;
        }

        if (t + 1 < NT) {
            __builtin_amdgcn_sched_barrier(0);
            const int rem = NT - 2 - t;   // tiles staged after t+1
            if (rem >= 2)      asm volatile("s_waitcnt vmcnt(8)" ::: "memory");
            else if (rem == 1) asm volatile("s_waitcnt vmcnt(4)" ::: "memory");
            else               asm volatile("s_waitcnt vmcnt(0)" ::: "memory");
            __builtin_amdgcn_s_barrier();
            __builtin_amdgcn_sched_barrier(0);
        }
    }

    // C/D layout: col = lane&15, row = (lane>>4)*4 + reg
    const int colb = n0 + wn * 64 + (lane & 15);
    const int rowb = m0 + wm * 128 + ((lane >> 4) << 2);

    if (EPI == 0 || EPI == 1) {
        _Float16* C = (_Float16*)Cv + (size_t)z * zsC;
        const long long ldc = 2 * (long long)N;
        #pragma unroll
        for (int mf = 0; mf < 8; ++mf)
            #pragma unroll
            for (int nf = 0; nf < 4; ++nf)
                #pragma unroll
                for (int r = 0; r < 4; ++r) {
                    const int row = rowb + mf * 16 + r;
                    const int col = colb + nf * 16;
                    float v = acc[mf][nf][r];
                    _Float16 h = (_Float16)v;
                    _Float16 l = (_Float16)((v - (float)h) * LO_SCALE);
                    if (EPI == 0) {
                        C[(size_t)row * ldc + col]     = h;
                        C[(size_t)row * ldc + N + col] = l;
                    } else {
                        C[(size_t)row * ldc + col]     = l;
                        C[(size_t)row * ldc + N + col] = h;
                    }
                }
    } else if (EPI == 2) {
        float* C = (float*)Cv + (size_t)z * zsC;
        #pragma unroll
        for (int mf = 0; mf < 8; ++mf)
            #pragma unroll
            for (int nf = 0; nf < 4; ++nf)
                #pragma unroll
                for (int r = 0; r < 4; ++r)
                    C[(size_t)(rowb + mf * 16 + r) * N + (colb + nf * 16)] = acc[mf][nf][r];
    } else if (EPI == 3) {
        _Float16* C = (_Float16*)Cv;   // VT: [batch][N][2048]
        #pragma unroll
        for (int mf = 0; mf < 8; ++mf) {
            const int row = rowb + mf * 16;
            const int bt = row >> 11, ml = row & 2047;
            #pragma unroll
            for (int nf = 0; nf < 4; ++nf) {
                union { _Float16 h[4]; short4 s4; } u;
                #pragma unroll
                for (int r = 0; r < 4; ++r) u.h[r] = (_Float16)acc[mf][nf][r];
                *(short4*)&C[(size_t)bt * (size_t)IDM * 2048 + (size_t)(colb + nf * 16) * 2048 + ml] = u.s4;
            }
        }
    } else if (EPI == 4) {
        _Float16* C = (_Float16*)Cv + (size_t)z * zsC;
        const float* E = (const float*)extraV + (size_t)z * zsE;
        #pragma unroll
        for (int mf = 0; mf < 8; ++mf)
            #pragma unroll
            for (int nf = 0; nf < 4; ++nf)
                #pragma unroll
                for (int r = 0; r < 4; ++r) {
                    const size_t idx = (size_t)(rowb + mf * 16 + r) * N + (colb + nf * 16);
                    C[idx] = (_Float16)(acc[mf][nf][r] + E[idx]);
                }
    } else if (EPI == 5) {
        float* C = (float*)Cv;
        const float* E = (const float*)extraV;
        #pragma unroll
        for (int mf = 0; mf < 8; ++mf)
            #pragma unroll
            for (int nf = 0; nf < 4; ++nf)
                #pragma unroll
                for (int r = 0; r < 4; ++r) {
                    const int row = rowb + mf * 16 + r;
                    const int col = colb + nf * 16;
                    float v = acc[mf][nf][r];
                    v = (v >= 0.f) ? v : NEG_SLOPE * v;
                    C[(size_t)row * N + col] = v + E[(size_t)(row & (LN - 1)) * N + col];
                }
    } else {  // EPI == 6: fused QK projection store
        _Float16* Cq = (_Float16*)Cv;                       // Qcat [M][2048] hi|lo
        _Float16* Ck = (_Float16*)const_cast<void*>(extraV);// Kcat [M][2048] lo|hi
        #pragma unroll
        for (int mf = 0; mf < 8; ++mf)
            #pragma unroll
            for (int nf = 0; nf < 4; ++nf)
                #pragma unroll
                for (int r = 0; r < 4; ++r) {
                    const int row = rowb + mf * 16 + r;
                    const int col = colb + nf * 16;        // 0..2047
                    float v = acc[mf][nf][r];
                    _Float16 h = (_Float16)v;
                    _Float16 l = (_Float16)((v - (float)h) * LO_SCALE);
                    if (col < 1024) {
                        Cq[(size_t)row * 2048 + col]        = h;
                        Cq[(size_t)row * 2048 + 1024 + col] = l;
                    } else {
                        Ck[(size_t)row * 2048 + col]        = h;
                        Ck[(size_t)row * 2048 + col - 1024] = l;
                    }
                }
    }
}

// ---------------------------------------------------------------------------
// i split: f32 [M][1024] -> f16 [M][2048]  (hi | lo*2^12)
__global__ __launch_bounds__(256) void split_i_k(
    const float* __restrict__ in, _Float16* __restrict__ out, long long n4)
{
    long long idx = (long long)blockIdx.x * 256 + threadIdx.x;
    if (idx >= n4) return;
    float4 v = ((const float4*)in)[idx];
    long long row = idx >> 8;
    int c4 = (int)(idx & 255) * 4;
    union { _Float16 h[4]; short4 s4; } hi, lo;
    float f0 = v.x; _Float16 h0 = (_Float16)f0; hi.h[0] = h0; lo.h[0] = (_Float16)((f0 - (float)h0) * LO_SCALE);
    float f1 = v.y; _Float16 h1 = (_Float16)f1; hi.h[1] = h1; lo.h[1] = (_Float16)((f1 - (float)h1) * LO_SCALE);
    float f2 = v.z; _Float16 h2 = (_Float16)f2; hi.h[2] = h2; lo.h[2] = (_Float16)((f2 - (float)h2) * LO_SCALE);
    float f3 = v.w; _Float16 h3 = (_Float16)f3; hi.h[3] = h3; lo.h[3] = (_Float16)((f3 - (float)h3) * LO_SCALE);
    *(short4*)&out[row * 2048 + c4]        = hi.s4;
    *(short4*)&out[row * 2048 + 1024 + c4] = lo.s4;
}

// weight transpose+split: in [K=1024][N=1024] f32 -> out [N][2048] (lo*2^12 | hi)
__global__ __launch_bounds__(256) void split_wT_k(
    const float* __restrict__ in, _Float16* __restrict__ out)
{
    __shared__ float t[32][33];
    const int bx = blockIdx.x * 32, by = blockIdx.y * 32;
    const int tx = threadIdx.x & 31, ty = threadIdx.x >> 5;
    #pragma unroll
    for (int i = 0; i < 32; i += 8)
        t[ty + i][tx] = in[(size_t)(by + ty + i) * 1024 + (bx + tx)];
    __syncthreads();
    #pragma unroll
    for (int i = 0; i < 32; i += 8) {
        float f = t[tx][ty + i];
        _Float16 h = (_Float16)f;
        _Float16 l = (_Float16)((f - (float)h) * LO_SCALE);
        const size_t n = bx + ty + i, k = by + tx;
        out[n * 2048 + k]        = l;
        out[n * 2048 + 1024 + k] = h;
    }
}

// plain transpose+convert: in [K=1024][N=1024] f32 -> out [N][1024] f16
__global__ __launch_bounds__(256) void transp_f32_f16(
    const float* __restrict__ in, _Float16* __restrict__ out)
{
    __shared__ float t[32][33];
    const int bx = blockIdx.x * 32, by = blockIdx.y * 32;
    const int tx = threadIdx.x & 31, ty = threadIdx.x >> 5;
    #pragma unroll
    for (int i = 0; i < 32; i += 8)
        t[ty + i][tx] = in[(size_t)(by + ty + i) * 1024 + (bx + tx)];
    __syncthreads();
    #pragma unroll
    for (int i = 0; i < 32; i += 8)
        out[(size_t)(bx + ty + i) * 1024 + (by + tx)] = (_Float16)t[tx][ty + i];
}

// in-place row softmax: S f32 row -> f16 written over the row's first half.
__global__ __launch_bounds__(256) void softmax_ip(float* __restrict__ S)
{
    const int tid = threadIdx.x;
    float* row = S + (size_t)blockIdx.y * LN * LN + (size_t)blockIdx.x * LN;

    float4 v0 = *(const float4*)&row[tid * 4];
    float4 v1 = *(const float4*)&row[1024 + tid * 4];

    float m = fmaxf(fmaxf(fmaxf(v0.x, v0.y), fmaxf(v0.z, v0.w)),
                    fmaxf(fmaxf(v1.x, v1.y), fmaxf(v1.z, v1.w)));
    #pragma unroll
    for (int off = 32; off > 0; off >>= 1) m = fmaxf(m, __shfl_xor(m, off));

    __shared__ float red[8];
    if ((tid & 63) == 0) red[tid >> 6] = m;
    __syncthreads();
    m = fmaxf(fmaxf(red[0], red[1]), fmaxf(red[2], red[3]));

    float e[8];
    e[0] = __expf(v0.x - m); e[1] = __expf(v0.y - m);
    e[2] = __expf(v0.z - m); e[3] = __expf(v0.w - m);
    e[4] = __expf(v1.x - m); e[5] = __expf(v1.y - m);
    e[6] = __expf(v1.z - m); e[7] = __expf(v1.w - m);
    float s = ((e[0] + e[1]) + (e[2] + e[3])) + ((e[4] + e[5]) + (e[6] + e[7]));
    #pragma unroll
    for (int off = 32; off > 0; off >>= 1) s += __shfl_xor(s, off);
    if ((tid & 63) == 0) red[4 + (tid >> 6)] = s;
    __syncthreads();
    s = (red[4] + red[5]) + (red[6] + red[7]);

    const float inv = 1.0f / s;
    _Float16* orow = (_Float16*)row;
    union { _Float16 h[4]; short4 s4; } a, b;
    a.h[0] = (_Float16)(e[0] * inv); a.h[1] = (_Float16)(e[1] * inv);
    a.h[2] = (_Float16)(e[2] * inv); a.h[3] = (_Float16)(e[3] * inv);
    b.h[0] = (_Float16)(e[4] * inv); b.h[1] = (_Float16)(e[5] * inv);
    b.h[2] = (_Float16)(e[6] * inv); b.h[3] = (_Float16)(e[7] * inv);
    *(short4*)&orow[tid * 4] = a.s4;
    *(short4*)&orow[1024 + tid * 4] = b.s4;
}

// ---------------------------------------------------------------------------
extern "C" void kernel_launch(void* const* d_in, const int* in_sizes, int n_in,
                              void* d_out, int out_size, void* d_ws, size_t ws_size,
                              hipStream_t stream)
{
    (void)in_sizes; (void)n_in; (void)out_size;
    const float* i_in  = (const float*)d_in[0];
    const float* k_w   = (const float*)d_in[1];
    const float* q_w   = (const float*)d_in[2];
    const float* v_w   = (const float*)d_in[3];
    const float* mlp_w = (const float*)d_in[4];
    const float* bias  = (const float*)d_in[5];
    float* out = (float*)d_out;

    (void)hipFuncSetAttribute((const void*)gemm256<2>, hipFuncAttributeMaxDynamicSharedMemorySize, 131072);
    (void)hipFuncSetAttribute((const void*)gemm256<3>, hipFuncAttributeMaxDynamicSharedMemorySize, 131072);
    (void)hipFuncSetAttribute((const void*)gemm256<4>, hipFuncAttributeMaxDynamicSharedMemorySize, 131072);
    (void)hipFuncSetAttribute((const void*)gemm256<5>, hipFuncAttributeMaxDynamicSharedMemorySize, 131072);
    (void)hipFuncSetAttribute((const void*)gemm256<6>, hipFuncAttributeMaxDynamicSharedMemorySize, 131072);

    char* ws = (char*)d_ws;
    const dim3 blk512(512);
    const dim3 blk256(256);
    const dim3 tgrid(32, 32);
    const size_t LDSB = 131072;

    const size_t MiB = 1ull << 20;
    const long long L2048 = 2048, L1024 = 1024, L4096 = 4096;

    if (ws_size >= 236 * MiB) {
        _Float16* Qcat  = (_Float16*)(ws);
        _Float16* Kcat  = (_Float16*)(ws + 64 * MiB);
        _Float16* VT    = (_Float16*)(ws + 128 * MiB);
        _Float16* qCatT = (_Float16*)(ws + 160 * MiB);   // contiguous with kCatT
        _Float16* kCatT = (_Float16*)(ws + 164 * MiB);
        _Float16* vT    = (_Float16*)(ws + 168 * MiB);
        _Float16* mlpT  = (_Float16*)(ws + 170 * MiB);
        _Float16* iCat  = (_Float16*)(ws + 172 * MiB);
        float*    sc    = (float*)(ws + 172 * MiB);     // 4 batches x 16 MiB
        _Float16* ret   = Qcat;                          // [16384][1024], 32 MiB

        split_i_k<<<dim3(16384), blk256, 0, stream>>>(i_in, iCat, (long long)NB * LN * IDM / 4);
        split_wT_k<<<tgrid, blk256, 0, stream>>>(q_w, qCatT);
        split_wT_k<<<tgrid, blk256, 0, stream>>>(k_w, kCatT);
        transp_f32_f16<<<tgrid, blk256, 0, stream>>>(v_w, vT);
        transp_f32_f16<<<tgrid, blk256, 0, stream>>>(mlp_w, mlpT);

        // fused Q+K projection: B rows 0-1023 = q weight, 1024-2047 = k weight
        gemm256<6><<<dim3(8, 64), blk512, LDSB, stream>>>(
            iCat, L2048, 1024, qCatT + 1024, L2048,
            iCat, L2048, 2048, qCatT, L2048,
            Kcat, Qcat, NB * LN, 2048, 0, 0, 0, 0);
        gemm256<3><<<dim3(4, 64), blk512, LDSB, stream>>>(
            iCat, L2048, 1024, vT, L1024,
            nullptr, 0, 0, nullptr, 0,
            nullptr, VT, NB * LN, 1024, 0, 0, 0, 0);
        // iCat now dead; sc aliases it.

        for (int c = 0; c < 2; ++c) {
            const size_t coff = (size_t)c * 4 * LN * 2048;
            gemm256<2><<<dim3(8, 8, 4), blk512, LDSB, stream>>>(
                Qcat + coff, L2048, 1024, Kcat + coff + 1024, L2048,
                Qcat + coff, L2048, 2048, Kcat + coff, L2048,
                nullptr, sc, LN, LN,
                (long long)LN * 2048, (long long)LN * 2048, (long long)LN * LN, 0);
            softmax_ip<<<dim3(LN, 4), blk256, 0, stream>>>(sc);
            gemm256<4><<<dim3(4, 8, 4), blk512, LDSB, stream>>>(
                (const _Float16*)sc, L4096, 2048, VT + (size_t)c * 4 * IDM * LN, L2048,
                nullptr, 0, 0, nullptr, 0,
                i_in + (size_t)c * 4 * LN * IDM, ret + (size_t)c * 4 * LN * IDM,
                LN, IDM,
                (long long)LN * LN * 2, (long long)IDM * LN, (long long)LN * IDM, (long long)LN * IDM);
        }
        gemm256<5><<<dim3(4, 64), blk512, LDSB, stream>>>(
            ret, L1024, 1024, mlpT, L1024,
            nullptr, 0, 0, nullptr, 0,
            bias, out, NB * LN, 1024, 0, 0, 0, 0);
    } else {
        // -------- small path (~60 MiB), per batch --------
        _Float16* qCatT = (_Float16*)(ws);               // contiguous with kCatT
        _Float16* kCatT = (_Float16*)(ws + 4 * MiB);
        _Float16* vT    = (_Float16*)(ws + 8 * MiB);
        _Float16* mlpT  = (_Float16*)(ws + 10 * MiB);
        _Float16* iCat  = (_Float16*)(ws + 12 * MiB);
        _Float16* Qcat  = (_Float16*)(ws + 20 * MiB);
        _Float16* Kcat  = (_Float16*)(ws + 28 * MiB);
        _Float16* VTb   = (_Float16*)(ws + 36 * MiB);
        float*    sc    = (float*)(ws + 40 * MiB);
        _Float16* ret   = (_Float16*)(ws + 56 * MiB);

        split_wT_k<<<tgrid, blk256, 0, stream>>>(q_w, qCatT);
        split_wT_k<<<tgrid, blk256, 0, stream>>>(k_w, kCatT);
        transp_f32_f16<<<tgrid, blk256, 0, stream>>>(v_w, vT);
        transp_f32_f16<<<tgrid, blk256, 0, stream>>>(mlp_w, mlpT);

        for (int b = 0; b < NB; ++b) {
            const size_t boff = (size_t)b * LN * IDM;
            split_i_k<<<dim3(2048), blk256, 0, stream>>>(i_in + boff, iCat, (long long)LN * IDM / 4);
            gemm256<6><<<dim3(8, 8), blk512, LDSB, stream>>>(
                iCat, L2048, 1024, qCatT + 1024, L2048,
                iCat, L2048, 2048, qCatT, L2048,
                Kcat, Qcat, LN, 2048, 0, 0, 0, 0);
            gemm256<3><<<dim3(4, 8), blk512, LDSB, stream>>>(
                iCat, L2048, 1024, vT, L1024,
                nullptr, 0, 0, nullptr, 0,
                nullptr, VTb, LN, 1024, 0, 0, 0, 0);
            gemm256<2><<<dim3(8, 8), blk512, LDSB, stream>>>(
                Qcat, L2048, 1024, Kcat + 1024, L2048,
                Qcat, L2048, 2048, Kcat, L2048,
                nullptr, sc, LN, LN, 0, 0, 0, 0);
            softmax_ip<<<dim3(LN, 1), blk256, 0, stream>>>(sc);
            gemm256<4><<<dim3(4, 8), blk512, LDSB, stream>>>(
                (const _Float16*)sc, L4096, 2048, VTb, L2048,
                nullptr, 0, 0, nullptr, 0,
                i_in + boff, ret, LN, IDM, 0, 0, 0, 0);
            gemm256<5><<<dim3(4, 8), blk512, LDSB, stream>>>(
                ret, L1024, 1024, mlpT, L1024,
                nullptr, 0, 0, nullptr, 0,
                bias, out + boff, LN, 1024, 0, 0, 0, 0);
        }
    }
}

// Round 8
// 706.848 us; speedup vs baseline: 2.0843x; 1.0566x over previous
//
#include <hip/hip_runtime.h>
#include <hip/hip_bf16.h>
#include <math.h>

#define LN   2048
#define IDM  1024
#define NB   8
#define NEG_SLOPE 0.2f
#define LO_SCALE   4096.0f      // 2^12: keeps lo parts out of f16 denormal range
#define LO_INV     (1.0f/4096.0f)

typedef _Float16 f16x8 __attribute__((ext_vector_type(8)));
typedef float    f32x4 __attribute__((ext_vector_type(4)));

#define GLDS16(g, l) \
    __builtin_amdgcn_global_load_lds((const __attribute__((address_space(1))) void*)(g), \
                                     (__attribute__((address_space(3))) void*)(l), 16, 0, 0)

extern __shared__ char smem[];   // 128 KiB: 2 step-buffers x (A 32K + B 32K)

// ---------------------------------------------------------------------------
// 256x256 tile, BK=64, 8 waves (2M x 4N), quadrant-phased K-loop (m201 port):
// per step (BK=64): 4 phases, one C-quadrant each, order (0,0),(0,1),(1,1),(1,0).
// Each phase: {ds_read subtile || stage half-tile of step s+1} -> lgkmcnt(0) ->
// setprio(1) 16 MFMA setprio(0); one s_barrier per phase; vmcnt(0) only at step
// entry (all 4 half-tiles needed; youngest in-flight ~2 phases old, L2-covered).
// LDS per step-buffer: A at +0, B at +32K; each: [half128][slab32][row][32 f16],
// slot-swizzle key (row>>1)&3 (inverse-applied on global source; zero-conflict,
// verified round 7).
// 2-segment K: (A2,B2,K2) correction first, then acc *= 2^-12, then (A1,B1,K1).
// A: [M][K] f16 rows (stride lda).  B: [N][K] f16 rows (stride ldb).
// EPI: 0 = split store hi|lo  (C f16 [M][2N]) ; 1 = split store lo|hi
//      2 = f32 store [M][N]
//      3 = f16 transposed per-2048-row-batch store: VT[b][N][2048]
//      4 = f16 store of (acc + E_f32[M][N])
//      5 = f32 store of leaky_relu(acc) + E_f32[row&2047][N]
//      6 = fused QK-proj store (N=2048): col<1024 -> Cv=Qcat hi|lo,
//          col>=1024 -> extraV=Kcat lo|hi (both [M][2048])
// ---------------------------------------------------------------------------
template<int EPI>
__global__ __launch_bounds__(512, 2) void gemm256(
    const _Float16* __restrict__ A1, long long lda1, int K1,
    const _Float16* __restrict__ B1, long long ldb1,
    const _Float16* __restrict__ A2, long long lda2, int K2,
    const _Float16* __restrict__ B2, long long ldb2,
    const void* __restrict__ extraV, void* __restrict__ Cv,
    int M, int N,
    long long zsA, long long zsB, long long zsC, long long zsE)
{
    const int tid  = threadIdx.x;

    // bijective XCD swizzle (all launch grids have nwg % 8 == 0)
    const unsigned nx = gridDim.x, ny = gridDim.y;
    const unsigned lid = blockIdx.x + nx * (blockIdx.y + ny * blockIdx.z);
    const unsigned cpx = (nx * ny * gridDim.z) >> 3;
    const unsigned swzid = (lid & 7) * cpx + (lid >> 3);
    const unsigned bx = swzid % nx, rest = swzid / nx;
    const unsigned by = rest % ny;
    const int z  = (int)(rest / ny);
    const int m0 = (int)by * 256, n0 = (int)bx * 256;

    const int lane = tid & 63;
    const int wid  = tid >> 6;
    const int wm   = wid >> 2;        // 0..1  (M half)
    const int wn   = wid & 3;         // 0..3  (N quarter)

    // staging: dest row = tid>>2 (0..127), dest slot = tid&3 (linear dest);
    // source col inverse-swizzled with key (destrow>>1)&3 = (tid>>3)&3
    const int sx   = ((tid & 3) ^ ((tid >> 3) & 3)) << 3;   // f16 units

    const int NT2 = K2 >> 6;
    const int NT  = NT2 + (K1 >> 6);

    const _Float16* A1z = A1 + (size_t)z * zsA;
    const _Float16* B1z = B1 + (size_t)z * zsB;
    const _Float16* A2z = (K2 > 0) ? A2 + (size_t)z * zsA : A1z;
    const _Float16* B2z = (K2 > 0) ? B2 + (size_t)z * zsB : B1z;

    // stage one 128-row half-tile (2 slabs of 32 k) of step st.
    // hh: 0 = A rows 0-127, 1 = A rows 128-255, 2 = B rows 0-127, 3 = B rows 128-255
    auto stageH = [&](int st, int hh) {
        if (st >= NT) return;
        const _Float16* P; long long ld; int kk;
        if (st < NT2) { P = (hh < 2) ? A2z : B2z; ld = (hh < 2) ? lda2 : ldb2; kk = st << 6; }
        else          { P = (hh < 2) ? A1z : B1z; ld = (hh < 2) ? lda1 : ldb1; kk = (st - NT2) << 6; }
        const int row0 = ((hh < 2) ? m0 : n0) + (hh & 1) * 128 + (tid >> 2);
        char* dst = smem + (size_t)(st & 1) * 65536 + ((hh >= 2) ? 32768 : 0)
                         + (hh & 1) * 16384 + tid * 16;
        const _Float16* src = P + (size_t)row0 * ld + kk + sx;
        GLDS16(src, dst);              // slab 0 (k 0-31)
        GLDS16(src + 32, dst + 8192);  // slab 1 (k 32-63)
    };

    const int fr   = lane & 15;
    const int ks4  = (((lane >> 4) ^ ((lane >> 1) & 3)) << 4);  // swizzled byte slot
    const int brow = (wn & 1) * 64 + fr;                        // B row base within half

    f32x4 acc[8][4] = {};
    f16x8 aF[4][2], bF[2][2];

    auto readA = [&](const char* bufA, int mh) {
        #pragma unroll
        for (int mf = 0; mf < 4; ++mf)
            #pragma unroll
            for (int sl = 0; sl < 2; ++sl)
                aF[mf][sl] = *(const f16x8*)(bufA + sl * 8192 + ((mh * 4 + mf) * 16 + fr) * 64 + ks4);
    };
    auto readB = [&](const char* bufB, int nh) {
        #pragma unroll
        for (int nf = 0; nf < 2; ++nf)
            #pragma unroll
            for (int sl = 0; sl < 2; ++sl)
                bF[nf][sl] = *(const f16x8*)(bufB + sl * 8192 + (brow + (nh * 2 + nf) * 16) * 64 + ks4);
    };
    auto mmaQ = [&](int mh, int nh) {
        __builtin_amdgcn_s_setprio(1);
        #pragma unroll
        for (int mf = 0; mf < 4; ++mf)
            #pragma unroll
            for (int nf = 0; nf < 2; ++nf)
                #pragma unroll
                for (int sl = 0; sl < 2; ++sl)
                    acc[mh * 4 + mf][nh * 2 + nf] = __builtin_amdgcn_mfma_f32_16x16x32_f16(
                        aF[mf][sl], bF[nf][sl], acc[mh * 4 + mf][nh * 2 + nf], 0, 0, 0);
        __builtin_amdgcn_s_setprio(0);
    };

    // prologue: stage step 0 (uniform loop entry; one cold stall only)
    stageH(0, 0); stageH(0, 1); stageH(0, 2); stageH(0, 3);

    #pragma unroll 1
    for (int s = 0; s < NT; ++s) {
        const char* base = smem + (size_t)(s & 1) * 65536;
        const char* bufA = base + wm * 16384;
        const char* bufB = base + 32768 + (wn >> 1) * 16384;

        // ---- phase 0: quadrant (0,0) ----
        asm volatile("s_waitcnt vmcnt(0)" ::: "memory");   // step s fully landed
        __builtin_amdgcn_s_barrier();
        __builtin_amdgcn_sched_barrier(0);
        readA(bufA, 0); readB(bufB, 0);
        stageH(s + 1, 0); stageH(s + 1, 1);
        asm volatile("s_waitcnt lgkmcnt(0)" ::: "memory");
        __builtin_amdgcn_sched_barrier(0);
        mmaQ(0, 0);

        // ---- phase 1: quadrant (0,1) ----
        __builtin_amdgcn_s_barrier();
        __builtin_amdgcn_sched_barrier(0);
        readB(bufB, 1);
        stageH(s + 1, 2);
        asm volatile("s_waitcnt lgkmcnt(0)" ::: "memory");
        __builtin_amdgcn_sched_barrier(0);
        mmaQ(0, 1);

        // ---- phase 2: quadrant (1,1) ----
        __builtin_amdgcn_s_barrier();
        __builtin_amdgcn_sched_barrier(0);
        readA(bufA, 1);
        stageH(s + 1, 3);
        asm volatile("s_waitcnt lgkmcnt(0)" ::: "memory");
        __builtin_amdgcn_sched_barrier(0);
        mmaQ(1, 1);

        // ---- phase 3: quadrant (1,0) ----
        __builtin_amdgcn_s_barrier();
        __builtin_amdgcn_sched_barrier(0);
        readB(bufB, 0);
        asm volatile("s_waitcnt lgkmcnt(0)" ::: "memory");
        __builtin_amdgcn_sched_barrier(0);
        mmaQ(1, 0);

        if (s == NT2 - 1) {
            #pragma unroll
            for (int mf = 0; mf < 8; ++mf)
                #pragma unroll
                for (int nf = 0; nf < 4; ++nf)
                    acc[mf][nf] *= LO_INV;
        }
    }

    // C/D layout: col = lane&15, row = (lane>>4)*4 + reg
    const int colb = n0 + wn * 64 + (lane & 15);
    const int rowb = m0 + wm * 128 + ((lane >> 4) << 2);

    if (EPI == 0 || EPI == 1) {
        _Float16* C = (_Float16*)Cv + (size_t)z * zsC;
        const long long ldc = 2 * (long long)N;
        #pragma unroll
        for (int mf = 0; mf < 8; ++mf)
            #pragma unroll
            for (int nf = 0; nf < 4; ++nf)
                #pragma unroll
                for (int r = 0; r < 4; ++r) {
                    const int row = rowb + mf * 16 + r;
                    const int col = colb + nf * 16;
                    float v = acc[mf][nf][r];
                    _Float16 h = (_Float16)v;
                    _Float16 l = (_Float16)((v - (float)h) * LO_SCALE);
                    if (EPI == 0) {
                        C[(size_t)row * ldc + col]     = h;
                        C[(size_t)row * ldc + N + col] = l;
                    } else {
                        C[(size_t)row * ldc + col]     = l;
                        C[(size_t)row * ldc + N + col] = h;
                    }
                }
    } else if (EPI == 2) {
        float* C = (float*)Cv + (size_t)z * zsC;
        #pragma unroll
        for (int mf = 0; mf < 8; ++mf)
            #pragma unroll
            for (int nf = 0; nf < 4; ++nf)
                #pragma unroll
                for (int r = 0; r < 4; ++r)
                    C[(size_t)(rowb + mf * 16 + r) * N + (colb + nf * 16)] = acc[mf][nf][r];
    } else if (EPI == 3) {
        _Float16* C = (_Float16*)Cv;   // VT: [batch][N][2048]
        #pragma unroll
        for (int mf = 0; mf < 8; ++mf) {
            const int row = rowb + mf * 16;
            const int bt = row >> 11, ml = row & 2047;
            #pragma unroll
            for (int nf = 0; nf < 4; ++nf) {
                union { _Float16 h[4]; short4 s4; } u;
                #pragma unroll
                for (int r = 0; r < 4; ++r) u.h[r] = (_Float16)acc[mf][nf][r];
                *(short4*)&C[(size_t)bt * (size_t)IDM * 2048 + (size_t)(colb + nf * 16) * 2048 + ml] = u.s4;
            }
        }
    } else if (EPI == 4) {
        _Float16* C = (_Float16*)Cv + (size_t)z * zsC;
        const float* E = (const float*)extraV + (size_t)z * zsE;
        #pragma unroll
        for (int mf = 0; mf < 8; ++mf)
            #pragma unroll
            for (int nf = 0; nf < 4; ++nf)
                #pragma unroll
                for (int r = 0; r < 4; ++r) {
                    const size_t idx = (size_t)(rowb + mf * 16 + r) * N + (colb + nf * 16);
                    C[idx] = (_Float16)(acc[mf][nf][r] + E[idx]);
                }
    } else if (EPI == 5) {
        float* C = (float*)Cv;
        const float* E = (const float*)extraV;
        #pragma unroll
        for (int mf = 0; mf < 8; ++mf)
            #pragma unroll
            for (int nf = 0; nf < 4; ++nf)
                #pragma unroll
                for (int r = 0; r < 4; ++r) {
                    const int row = rowb + mf * 16 + r;
                    const int col = colb + nf * 16;
                    float v = acc[mf][nf][r];
                    v = (v >= 0.f) ? v : NEG_SLOPE * v;
                    C[(size_t)row * N + col] = v + E[(size_t)(row & (LN - 1)) * N + col];
                }
    } else {  // EPI == 6: fused QK projection store
        _Float16* Cq = (_Float16*)Cv;                       // Qcat [M][2048] hi|lo
        _Float16* Ck = (_Float16*)const_cast<void*>(extraV);// Kcat [M][2048] lo|hi
        #pragma unroll
        for (int mf = 0; mf < 8; ++mf)
            #pragma unroll
            for (int nf = 0; nf < 4; ++nf)
                #pragma unroll
                for (int r = 0; r < 4; ++r) {
                    const int row = rowb + mf * 16 + r;
                    const int col = colb + nf * 16;        // 0..2047
                    float v = acc[mf][nf][r];
                    _Float16 h = (_Float16)v;
                    _Float16 l = (_Float16)((v - (float)h) * LO_SCALE);
                    if (col < 1024) {
                        Cq[(size_t)row * 2048 + col]        = h;
                        Cq[(size_t)row * 2048 + 1024 + col] = l;
                    } else {
                        Ck[(size_t)row * 2048 + col]        = h;
                        Ck[(size_t)row * 2048 + col - 1024] = l;
                    }
                }
    }
}

// ---------------------------------------------------------------------------
// i split: f32 [M][1024] -> f16 [M][2048]  (hi | lo*2^12)
__global__ __launch_bounds__(256) void split_i_k(
    const float* __restrict__ in, _Float16* __restrict__ out, long long n4)
{
    long long idx = (long long)blockIdx.x * 256 + threadIdx.x;
    if (idx >= n4) return;
    float4 v = ((const float4*)in)[idx];
    long long row = idx >> 8;
    int c4 = (int)(idx & 255) * 4;
    union { _Float16 h[4]; short4 s4; } hi, lo;
    float f0 = v.x; _Float16 h0 = (_Float16)f0; hi.h[0] = h0; lo.h[0] = (_Float16)((f0 - (float)h0) * LO_SCALE);
    float f1 = v.y; _Float16 h1 = (_Float16)f1; hi.h[1] = h1; lo.h[1] = (_Float16)((f1 - (float)h1) * LO_SCALE);
    float f2 = v.z; _Float16 h2 = (_Float16)f2; hi.h[2] = h2; lo.h[2] = (_Float16)((f2 - (float)h2) * LO_SCALE);
    float f3 = v.w; _Float16 h3 = (_Float16)f3; hi.h[3] = h3; lo.h[3] = (_Float16)((f3 - (float)h3) * LO_SCALE);
    *(short4*)&out[row * 2048 + c4]        = hi.s4;
    *(short4*)&out[row * 2048 + 1024 + c4] = lo.s4;
}

// weight transpose+split: in [K=1024][N=1024] f32 -> out [N][2048] (lo*2^12 | hi)
__global__ __launch_bounds__(256) void split_wT_k(
    const float* __restrict__ in, _Float16* __restrict__ out)
{
    __shared__ float t[32][33];
    const int bx = blockIdx.x * 32, by = blockIdx.y * 32;
    const int tx = threadIdx.x & 31, ty = threadIdx.x >> 5;
    #pragma unroll
    for (int i = 0; i < 32; i += 8)
        t[ty + i][tx] = in[(size_t)(by + ty + i) * 1024 + (bx + tx)];
    __syncthreads();
    #pragma unroll
    for (int i = 0; i < 32; i += 8) {
        float f = t[tx][ty + i];
        _Float16 h = (_Float16)f;
        _Float16 l = (_Float16)((f - (float)h) * LO_SCALE);
        const size_t n = bx + ty + i, k = by + tx;
        out[n * 2048 + k]        = l;
        out[n * 2048 + 1024 + k] = h;
    }
}

// plain transpose+convert: in [K=1024][N=1024] f32 -> out [N][1024] f16
__global__ __launch_bounds__(256) void transp_f32_f16(
    const float* __restrict__ in, _Float16* __restrict__ out)
{
    __shared__ float t[32][33];
    const int bx = blockIdx.x * 32, by = blockIdx.y * 32;
    const int tx = threadIdx.x & 31, ty = threadIdx.x >> 5;
    #pragma unroll
    for (int i = 0; i < 32; i += 8)
        t[ty + i][tx] = in[(size_t)(by + ty + i) * 1024 + (bx + tx)];
    __syncthreads();
    #pragma unroll
    for (int i = 0; i < 32; i += 8)
        out[(size_t)(bx + ty + i) * 1024 + (by + tx)] = (_Float16)t[tx][ty + i];
}

// in-place row softmax: S f32 row -> f16 written over the row's first half.
__global__ __launch_bounds__(256) void softmax_ip(float* __restrict__ S)
{
    const int tid = threadIdx.x;
    float* row = S + (size_t)blockIdx.y * LN * LN + (size_t)blockIdx.x * LN;

    float4 v0 = *(const float4*)&row[tid * 4];
    float4 v1 = *(const float4*)&row[1024 + tid * 4];

    float m = fmaxf(fmaxf(fmaxf(v0.x, v0.y), fmaxf(v0.z, v0.w)),
                    fmaxf(fmaxf(v1.x, v1.y), fmaxf(v1.z, v1.w)));
    #pragma unroll
    for (int off = 32; off > 0; off >>= 1) m = fmaxf(m, __shfl_xor(m, off));

    __shared__ float red[8];
    if ((tid & 63) == 0) red[tid >> 6] = m;
    __syncthreads();
    m = fmaxf(fmaxf(red[0], red[1]), fmaxf(red[2], red[3]));

    float e[8];
    e[0] = __expf(v0.x - m); e[1] = __expf(v0.y - m);
    e[2] = __expf(v0.z - m); e[3] = __expf(v0.w - m);
    e[4] = __expf(v1.x - m); e[5] = __expf(v1.y - m);
    e[6] = __expf(v1.z - m); e[7] = __expf(v1.w - m);
    float s = ((e[0] + e[1]) + (e[2] + e[3])) + ((e[4] + e[5]) + (e[6] + e[7]));
    #pragma unroll
    for (int off = 32; off > 0; off >>= 1) s += __shfl_xor(s, off);
    if ((tid & 63) == 0) red[4 + (tid >> 6)] = s;
    __syncthreads();
    s = (red[4] + red[5]) + (red[6] + red[7]);

    const float inv = 1.0f / s;
    _Float16* orow = (_Float16*)row;
    union { _Float16 h[4]; short4 s4; } a, b;
    a.h[0] = (_Float16)(e[0] * inv); a.h[1] = (_Float16)(e[1] * inv);
    a.h[2] = (_Float16)(e[2] * inv); a.h[3] = (_Float16)(e[3] * inv);
    b.h[0] = (_Float16)(e[4] * inv); b.h[1] = (_Float16)(e[5] * inv);
    b.h[2] = (_Float16)(e[6] * inv); b.h[3] = (_Float16)(e[7] * inv);
    *(short4*)&orow[tid * 4] = a.s4;
    *(short4*)&orow[1024 + tid * 4] = b.s4;
}

// ---------------------------------------------------------------------------
extern "C" void kernel_launch(void* const* d_in, const int* in_sizes, int n_in,
                              void* d_out, int out_size, void* d_ws, size_t ws_size,
                              hipStream_t stream)
{
    (void)in_sizes; (void)n_in; (void)out_size;
    const float* i_in  = (const float*)d_in[0];
    const float* k_w   = (const float*)d_in[1];
    const float* q_w   = (const float*)d_in[2];
    const float* v_w   = (const float*)d_in[3];
    const float* mlp_w = (const float*)d_in[4];
    const float* bias  = (const float*)d_in[5];
    float* out = (float*)d_out;

    (void)hipFuncSetAttribute((const void*)gemm256<2>, hipFuncAttributeMaxDynamicSharedMemorySize, 131072);
    (void)hipFuncSetAttribute((const void*)gemm256<3>, hipFuncAttributeMaxDynamicSharedMemorySize, 131072);
    (void)hipFuncSetAttribute((const void*)gemm256<4>, hipFuncAttributeMaxDynamicSharedMemorySize, 131072);
    (void)hipFuncSetAttribute((const void*)gemm256<5>, hipFuncAttributeMaxDynamicSharedMemorySize, 131072);
    (void)hipFuncSetAttribute((const void*)gemm256<6>, hipFuncAttributeMaxDynamicSharedMemorySize, 131072);

    char* ws = (char*)d_ws;
    const dim3 blk512(512);
    const dim3 blk256(256);
    const dim3 tgrid(32, 32);
    const size_t LDSB = 131072;

    const size_t MiB = 1ull << 20;
    const long long L2048 = 2048, L1024 = 1024, L4096 = 4096;

    if (ws_size >= 236 * MiB) {
        _Float16* Qcat  = (_Float16*)(ws);
        _Float16* Kcat  = (_Float16*)(ws + 64 * MiB);
        _Float16* VT    = (_Float16*)(ws + 128 * MiB);
        _Float16* qCatT = (_Float16*)(ws + 160 * MiB);   // contiguous with kCatT
        _Float16* kCatT = (_Float16*)(ws + 164 * MiB);
        _Float16* vT    = (_Float16*)(ws + 168 * MiB);
        _Float16* mlpT  = (_Float16*)(ws + 170 * MiB);
        _Float16* iCat  = (_Float16*)(ws + 172 * MiB);
        float*    sc    = (float*)(ws + 172 * MiB);     // 4 batches x 16 MiB
        _Float16* ret   = Qcat;                          // [16384][1024], 32 MiB

        split_i_k<<<dim3(16384), blk256, 0, stream>>>(i_in, iCat, (long long)NB * LN * IDM / 4);
        split_wT_k<<<tgrid, blk256, 0, stream>>>(q_w, qCatT);
        split_wT_k<<<tgrid, blk256, 0, stream>>>(k_w, kCatT);
        transp_f32_f16<<<tgrid, blk256, 0, stream>>>(v_w, vT);
        transp_f32_f16<<<tgrid, blk256, 0, stream>>>(mlp_w, mlpT);

        // fused Q+K projection: B rows 0-1023 = q weight, 1024-2047 = k weight
        gemm256<6><<<dim3(8, 64), blk512, LDSB, stream>>>(
            iCat, L2048, 1024, qCatT + 1024, L2048,
            iCat, L2048, 2048, qCatT, L2048,
            Kcat, Qcat, NB * LN, 2048, 0, 0, 0, 0);
        gemm256<3><<<dim3(4, 64), blk512, LDSB, stream>>>(
            iCat, L2048, 1024, vT, L1024,
            nullptr, 0, 0, nullptr, 0,
            nullptr, VT, NB * LN, 1024, 0, 0, 0, 0);
        // iCat now dead; sc aliases it.

        for (int c = 0; c < 2; ++c) {
            const size_t coff = (size_t)c * 4 * LN * 2048;
            gemm256<2><<<dim3(8, 8, 4), blk512, LDSB, stream>>>(
                Qcat + coff, L2048, 1024, Kcat + coff + 1024, L2048,
                Qcat + coff, L2048, 2048, Kcat + coff, L2048,
                nullptr, sc, LN, LN,
                (long long)LN * 2048, (long long)LN * 2048, (long long)LN * LN, 0);
            softmax_ip<<<dim3(LN, 4), blk256, 0, stream>>>(sc);
            gemm256<4><<<dim3(4, 8, 4), blk512, LDSB, stream>>>(
                (const _Float16*)sc, L4096, 2048, VT + (size_t)c * 4 * IDM * LN, L2048,
                nullptr, 0, 0, nullptr, 0,
                i_in + (size_t)c * 4 * LN * IDM, ret + (size_t)c * 4 * LN * IDM,
                LN, IDM,
                (long long)LN * LN * 2, (long long)IDM * LN, (long long)LN * IDM, (long long)LN * IDM);
        }
        gemm256<5><<<dim3(4, 64), blk512, LDSB, stream>>>(
            ret, L1024, 1024, mlpT, L1024,
            nullptr, 0, 0, nullptr, 0,
            bias, out, NB * LN, 1024, 0, 0, 0, 0);
    } else {
        // -------- small path (~60 MiB), per batch --------
        _Float16* qCatT = (_Float16*)(ws);               // contiguous with kCatT
        _Float16* kCatT = (_Float16*)(ws + 4 * MiB);
        _Float16* vT    = (_Float16*)(ws + 8 * MiB);
        _Float16* mlpT  = (_Float16*)(ws + 10 * MiB);
        _Float16* iCat  = (_Float16*)(ws + 12 * MiB);
        _Float16* Qcat  = (_Float16*)(ws + 20 * MiB);
        _Float16* Kcat  = (_Float16*)(ws + 28 * MiB);
        _Float16* VTb   = (_Float16*)(ws + 36 * MiB);
        float*    sc    = (float*)(ws + 40 * MiB);
        _Float16* ret   = (_Float16*)(ws + 56 * MiB);

        split_wT_k<<<tgrid, blk256, 0, stream>>>(q_w, qCatT);
        split_wT_k<<<tgrid, blk256, 0, stream>>>(k_w, kCatT);
        transp_f32_f16<<<tgrid, blk256, 0, stream>>>(v_w, vT);
        transp_f32_f16<<<tgrid, blk256, 0, stream>>>(mlp_w, mlpT);

        for (int b = 0; b < NB; ++b) {
            const size_t boff = (size_t)b * LN * IDM;
            split_i_k<<<dim3(2048), blk256, 0, stream>>>(i_in + boff, iCat, (long long)LN * IDM / 4);
            gemm256<6><<<dim3(8, 8), blk512, LDSB, stream>>>(
                iCat, L2048, 1024, qCatT + 1024, L2048,
                iCat, L2048, 2048, qCatT, L2048,
                Kcat, Qcat, LN, 2048, 0, 0, 0, 0);
            gemm256<3><<<dim3(4, 8), blk512, LDSB, stream>>>(
                iCat, L2048, 1024, vT, L1024,
                nullptr, 0, 0, nullptr, 0,
                nullptr, VTb, LN, 1024, 0, 0, 0, 0);
            gemm256<2><<<dim3(8, 8), blk512, LDSB, stream>>>(
                Qcat, L2048, 1024, Kcat + 1024, L2048,
                Qcat, L2048, 2048, Kcat, L2048,
                nullptr, sc, LN, LN, 0, 0, 0, 0);
            softmax_ip<<<dim3(LN, 1), blk256, 0, stream>>>(sc);
            gemm256<4><<<dim3(4, 8), blk512, LDSB, stream>>>(
                (const _Float16*)sc, L4096, 2048, VTb, L2048,
                nullptr, 0, 0, nullptr, 0,
                i_in + boff, ret, LN, IDM, 0, 0, 0, 0);
            gemm256<5><<<dim3(4, 8), blk512, LDSB, stream>>>(
                ret, L1024, 1024, mlpT, L1024,
                nullptr, 0, 0, nullptr, 0,
                bias, out + boff, LN, 1024, 0, 0, 0, 0);
        }
    }
}

// Round 9
// 647.486 us; speedup vs baseline: 2.2754x; 1.0917x over previous
//
#include <hip/hip_runtime.h>
#include <hip/hip_bf16.h>
#include <math.h>

#define LN   2048
#define IDM  1024
#define NB   8
#define NEG_SLOPE 0.2f
#define LO_SCALE   4096.0f      // 2^12: keeps lo parts out of f16 denormal range
#define LO_INV     (1.0f/4096.0f)

typedef _Float16 f16x8 __attribute__((ext_vector_type(8)));
typedef float    f32x4 __attribute__((ext_vector_type(4)));

#define GLDS16(g, l) \
    __builtin_amdgcn_global_load_lds((const __attribute__((address_space(1))) void*)(g), \
                                     (__attribute__((address_space(3))) void*)(l), 16, 0, 0)

extern __shared__ char smem[];   // 128 KiB: 2 step-buffers x (A 32K + B 32K)

// ---------------------------------------------------------------------------
// 256x256 tile, BK=64, 8 waves (2M x 4N), quadrant-phased K-loop.
// Per step: 3 barrier-regions: {stage A0,A1 | read aF[mh0],bFn[0] | 16 MFMA},
// {stage B0 | read bFn[1] | 16 MFMA}, {stage B1 | read aF[mh1] | 32 MFMA}.
// All 8 B-fragments cached in regs (no re-read; 192 KB LDS/step vs 224 prev).
// vmcnt(0) only at step entry (loads there are >=2 phases old).
// LDS slot-swizzle key (row>>1)&3, inverse-applied on global source
// (zero-conflict, verified round 7).
// 2-segment K: (A2,B2,K2) correction first, then acc *= 2^-12, then (A1,B1,K1).
// A: [M][K] f16 rows (stride lda).  B: [N][K] f16 rows (stride ldb).
// EPI: 0 = split store hi|lo  (C f16 [M][2N]) ; 1 = split store lo|hi
//      2 = f32 store [M][N]
//      3 = f16 transposed per-2048-row-batch store: VT[b][N][2048]
//      4 = f16 store of (acc + E_f32[M][N])
//      5 = f32 store of leaky_relu(acc) + E_f32[row&2047][N]
//      6 = fused QK-proj store (N=2048): col<1024 -> Cv=Qcat hi|lo,
//          col>=1024 -> extraV=Kcat lo|hi (both [M][2048])
// ---------------------------------------------------------------------------
template<int EPI>
__global__ __launch_bounds__(512, 2) void gemm256(
    const _Float16* __restrict__ A1, long long lda1, int K1,
    const _Float16* __restrict__ B1, long long ldb1,
    const _Float16* __restrict__ A2, long long lda2, int K2,
    const _Float16* __restrict__ B2, long long ldb2,
    const void* __restrict__ extraV, void* __restrict__ Cv,
    int M, int N,
    long long zsA, long long zsB, long long zsC, long long zsE)
{
    const int tid  = threadIdx.x;

    // bijective XCD swizzle (all launch grids have nwg % 8 == 0)
    const unsigned nx = gridDim.x, ny = gridDim.y;
    const unsigned lid = blockIdx.x + nx * (blockIdx.y + ny * blockIdx.z);
    const unsigned cpx = (nx * ny * gridDim.z) >> 3;
    const unsigned swzid = (lid & 7) * cpx + (lid >> 3);
    const unsigned bx = swzid % nx, rest = swzid / nx;
    const unsigned by = rest % ny;
    const int z  = (int)(rest / ny);
    const int m0 = (int)by * 256, n0 = (int)bx * 256;

    const int lane = tid & 63;
    const int wid  = tid >> 6;
    const int wm   = wid >> 2;        // 0..1  (M half)
    const int wn   = wid & 3;         // 0..3  (N quarter)

    // staging: dest row = tid>>2 (0..127), dest slot = tid&3 (linear dest);
    // source col inverse-swizzled with key (destrow>>1)&3 = (tid>>3)&3
    const int sx   = ((tid & 3) ^ ((tid >> 3) & 3)) << 3;   // f16 units

    const int NT2 = K2 >> 6;
    const int NT  = NT2 + (K1 >> 6);

    const _Float16* A1z = A1 + (size_t)z * zsA;
    const _Float16* B1z = B1 + (size_t)z * zsB;
    const _Float16* A2z = (K2 > 0) ? A2 + (size_t)z * zsA : A1z;
    const _Float16* B2z = (K2 > 0) ? B2 + (size_t)z * zsB : B1z;

    // stage one 128-row half-tile (2 slabs of 32 k) of step st.
    // hh: 0 = A rows 0-127, 1 = A rows 128-255, 2 = B rows 0-127, 3 = B rows 128-255
    auto stageH = [&](int st, int hh) {
        if (st >= NT) return;
        const _Float16* P; long long ld; int kk;
        if (st < NT2) { P = (hh < 2) ? A2z : B2z; ld = (hh < 2) ? lda2 : ldb2; kk = st << 6; }
        else          { P = (hh < 2) ? A1z : B1z; ld = (hh < 2) ? lda1 : ldb1; kk = (st - NT2) << 6; }
        const int row0 = ((hh < 2) ? m0 : n0) + (hh & 1) * 128 + (tid >> 2);
        char* dst = smem + (size_t)(st & 1) * 65536 + ((hh >= 2) ? 32768 : 0)
                         + (hh & 1) * 16384 + tid * 16;
        const _Float16* src = P + (size_t)row0 * ld + kk + sx;
        GLDS16(src, dst);              // slab 0 (k 0-31)
        GLDS16(src + 32, dst + 8192);  // slab 1 (k 32-63)
    };

    const int fr   = lane & 15;
    const int ks4  = (((lane >> 4) ^ ((lane >> 1) & 3)) << 4);  // swizzled byte slot
    const int brow = (wn & 1) * 64 + fr;                        // B row base within half

    f32x4 acc[8][4] = {};
    f16x8 aF[4][2];          // current m-half fragments
    f16x8 bFn[2][2][2];      // [nh][nf][slab] — all 8 B frags cached

    auto readA = [&](const char* bufA, int mh) {
        #pragma unroll
        for (int mf = 0; mf < 4; ++mf)
            #pragma unroll
            for (int sl = 0; sl < 2; ++sl)
                aF[mf][sl] = *(const f16x8*)(bufA + sl * 8192 + ((mh * 4 + mf) * 16 + fr) * 64 + ks4);
    };
    auto readB = [&](const char* bufB, int nh) {
        #pragma unroll
        for (int nf = 0; nf < 2; ++nf)
            #pragma unroll
            for (int sl = 0; sl < 2; ++sl)
                bFn[nh][nf][sl] = *(const f16x8*)(bufB + sl * 8192 + (brow + (nh * 2 + nf) * 16) * 64 + ks4);
    };
    auto mmaQ = [&](int mh, int nh) {
        __builtin_amdgcn_s_setprio(1);
        #pragma unroll
        for (int mf = 0; mf < 4; ++mf)
            #pragma unroll
            for (int nf = 0; nf < 2; ++nf)
                #pragma unroll
                for (int sl = 0; sl < 2; ++sl)
                    acc[mh * 4 + mf][nh * 2 + nf] = __builtin_amdgcn_mfma_f32_16x16x32_f16(
                        aF[mf][sl], bFn[nh][nf][sl], acc[mh * 4 + mf][nh * 2 + nf], 0, 0, 0);
        __builtin_amdgcn_s_setprio(0);
    };

    // prologue: stage step 0
    stageH(0, 0); stageH(0, 1); stageH(0, 2); stageH(0, 3);

    #pragma unroll 1
    for (int s = 0; s < NT; ++s) {
        const char* base = smem + (size_t)(s & 1) * 65536;
        const char* bufA = base + wm * 16384;
        const char* bufB = base + 32768 + (wn >> 1) * 16384;

        // ---- region 0: quadrant (0,0) ----
        asm volatile("s_waitcnt vmcnt(0)" ::: "memory");   // step s fully landed
        __builtin_amdgcn_s_barrier();
        __builtin_amdgcn_sched_barrier(0);
        stageH(s + 1, 0); stageH(s + 1, 1);
        readA(bufA, 0); readB(bufB, 0);
        asm volatile("s_waitcnt lgkmcnt(0)" ::: "memory");
        __builtin_amdgcn_sched_barrier(0);
        mmaQ(0, 0);

        // ---- region 1: quadrant (0,1) ----
        __builtin_amdgcn_s_barrier();
        __builtin_amdgcn_sched_barrier(0);
        stageH(s + 1, 2);
        readB(bufB, 1);
        asm volatile("s_waitcnt lgkmcnt(0)" ::: "memory");
        __builtin_amdgcn_sched_barrier(0);
        mmaQ(0, 1);

        // ---- region 2: quadrants (1,1) then (1,0) — B cached, no re-read ----
        __builtin_amdgcn_s_barrier();
        __builtin_amdgcn_sched_barrier(0);
        stageH(s + 1, 3);
        readA(bufA, 1);
        asm volatile("s_waitcnt lgkmcnt(0)" ::: "memory");
        __builtin_amdgcn_sched_barrier(0);
        mmaQ(1, 1);
        mmaQ(1, 0);

        if (s == NT2 - 1) {
            #pragma unroll
            for (int mf = 0; mf < 8; ++mf)
                #pragma unroll
                for (int nf = 0; nf < 4; ++nf)
                    acc[mf][nf] *= LO_INV;
        }
    }

    // C/D layout: col = lane&15, row = (lane>>4)*4 + reg
    const int colb = n0 + wn * 64 + (lane & 15);
    const int rowb = m0 + wm * 128 + ((lane >> 4) << 2);

    if (EPI == 0 || EPI == 1) {
        _Float16* C = (_Float16*)Cv + (size_t)z * zsC;
        const long long ldc = 2 * (long long)N;
        #pragma unroll
        for (int mf = 0; mf < 8; ++mf)
            #pragma unroll
            for (int nf = 0; nf < 4; ++nf)
                #pragma unroll
                for (int r = 0; r < 4; ++r) {
                    const int row = rowb + mf * 16 + r;
                    const int col = colb + nf * 16;
                    float v = acc[mf][nf][r];
                    _Float16 h = (_Float16)v;
                    _Float16 l = (_Float16)((v - (float)h) * LO_SCALE);
                    if (EPI == 0) {
                        C[(size_t)row * ldc + col]     = h;
                        C[(size_t)row * ldc + N + col] = l;
                    } else {
                        C[(size_t)row * ldc + col]     = l;
                        C[(size_t)row * ldc + N + col] = h;
                    }
                }
    } else if (EPI == 2) {
        float* C = (float*)Cv + (size_t)z * zsC;
        #pragma unroll
        for (int mf = 0; mf < 8; ++mf)
            #pragma unroll
            for (int nf = 0; nf < 4; ++nf)
                #pragma unroll
                for (int r = 0; r < 4; ++r)
                    C[(size_t)(rowb + mf * 16 + r) * N + (colb + nf * 16)] = acc[mf][nf][r];
    } else if (EPI == 3) {
        _Float16* C = (_Float16*)Cv;   // VT: [batch][N][2048]
        #pragma unroll
        for (int mf = 0; mf < 8; ++mf) {
            const int row = rowb + mf * 16;
            const int bt = row >> 11, ml = row & 2047;
            #pragma unroll
            for (int nf = 0; nf < 4; ++nf) {
                union { _Float16 h[4]; short4 s4; } u;
                #pragma unroll
                for (int r = 0; r < 4; ++r) u.h[r] = (_Float16)acc[mf][nf][r];
                *(short4*)&C[(size_t)bt * (size_t)IDM * 2048 + (size_t)(colb + nf * 16) * 2048 + ml] = u.s4;
            }
        }
    } else if (EPI == 4) {
        _Float16* C = (_Float16*)Cv + (size_t)z * zsC;
        const float* E = (const float*)extraV + (size_t)z * zsE;
        #pragma unroll
        for (int mf = 0; mf < 8; ++mf)
            #pragma unroll
            for (int nf = 0; nf < 4; ++nf)
                #pragma unroll
                for (int r = 0; r < 4; ++r) {
                    const size_t idx = (size_t)(rowb + mf * 16 + r) * N + (colb + nf * 16);
                    C[idx] = (_Float16)(acc[mf][nf][r] + E[idx]);
                }
    } else if (EPI == 5) {
        float* C = (float*)Cv;
        const float* E = (const float*)extraV;
        #pragma unroll
        for (int mf = 0; mf < 8; ++mf)
            #pragma unroll
            for (int nf = 0; nf < 4; ++nf)
                #pragma unroll
                for (int r = 0; r < 4; ++r) {
                    const int row = rowb + mf * 16 + r;
                    const int col = colb + nf * 16;
                    float v = acc[mf][nf][r];
                    v = (v >= 0.f) ? v : NEG_SLOPE * v;
                    C[(size_t)row * N + col] = v + E[(size_t)(row & (LN - 1)) * N + col];
                }
    } else {  // EPI == 6: fused QK projection store
        _Float16* Cq = (_Float16*)Cv;                       // Qcat [M][2048] hi|lo
        _Float16* Ck = (_Float16*)const_cast<void*>(extraV);// Kcat [M][2048] lo|hi
        #pragma unroll
        for (int mf = 0; mf < 8; ++mf)
            #pragma unroll
            for (int nf = 0; nf < 4; ++nf)
                #pragma unroll
                for (int r = 0; r < 4; ++r) {
                    const int row = rowb + mf * 16 + r;
                    const int col = colb + nf * 16;        // 0..2047
                    float v = acc[mf][nf][r];
                    _Float16 h = (_Float16)v;
                    _Float16 l = (_Float16)((v - (float)h) * LO_SCALE);
                    if (col < 1024) {
                        Cq[(size_t)row * 2048 + col]        = h;
                        Cq[(size_t)row * 2048 + 1024 + col] = l;
                    } else {
                        Ck[(size_t)row * 2048 + col]        = h;
                        Ck[(size_t)row * 2048 + col - 1024] = l;
                    }
                }
    }
}

// ---------------------------------------------------------------------------
// i split: f32 [M][1024] -> f16 [M][2048]  (hi | lo*2^12)
__global__ __launch_bounds__(256) void split_i_k(
    const float* __restrict__ in, _Float16* __restrict__ out, long long n4)
{
    long long idx = (long long)blockIdx.x * 256 + threadIdx.x;
    if (idx >= n4) return;
    float4 v = ((const float4*)in)[idx];
    long long row = idx >> 8;
    int c4 = (int)(idx & 255) * 4;
    union { _Float16 h[4]; short4 s4; } hi, lo;
    float f0 = v.x; _Float16 h0 = (_Float16)f0; hi.h[0] = h0; lo.h[0] = (_Float16)((f0 - (float)h0) * LO_SCALE);
    float f1 = v.y; _Float16 h1 = (_Float16)f1; hi.h[1] = h1; lo.h[1] = (_Float16)((f1 - (float)h1) * LO_SCALE);
    float f2 = v.z; _Float16 h2 = (_Float16)f2; hi.h[2] = h2; lo.h[2] = (_Float16)((f2 - (float)h2) * LO_SCALE);
    float f3 = v.w; _Float16 h3 = (_Float16)f3; hi.h[3] = h3; lo.h[3] = (_Float16)((f3 - (float)h3) * LO_SCALE);
    *(short4*)&out[row * 2048 + c4]        = hi.s4;
    *(short4*)&out[row * 2048 + 1024 + c4] = lo.s4;
}

// weight transpose+split: in [K=1024][N=1024] f32 -> out [N][2048] (lo*2^12 | hi)
__global__ __launch_bounds__(256) void split_wT_k(
    const float* __restrict__ in, _Float16* __restrict__ out)
{
    __shared__ float t[32][33];
    const int bx = blockIdx.x * 32, by = blockIdx.y * 32;
    const int tx = threadIdx.x & 31, ty = threadIdx.x >> 5;
    #pragma unroll
    for (int i = 0; i < 32; i += 8)
        t[ty + i][tx] = in[(size_t)(by + ty + i) * 1024 + (bx + tx)];
    __syncthreads();
    #pragma unroll
    for (int i = 0; i < 32; i += 8) {
        float f = t[tx][ty + i];
        _Float16 h = (_Float16)f;
        _Float16 l = (_Float16)((f - (float)h) * LO_SCALE);
        const size_t n = bx + ty + i, k = by + tx;
        out[n * 2048 + k]        = l;
        out[n * 2048 + 1024 + k] = h;
    }
}

// plain transpose+convert: in [K=1024][N=1024] f32 -> out [N][1024] f16
__global__ __launch_bounds__(256) void transp_f32_f16(
    const float* __restrict__ in, _Float16* __restrict__ out)
{
    __shared__ float t[32][33];
    const int bx = blockIdx.x * 32, by = blockIdx.y * 32;
    const int tx = threadIdx.x & 31, ty = threadIdx.x >> 5;
    #pragma unroll
    for (int i = 0; i < 32; i += 8)
        t[ty + i][tx] = in[(size_t)(by + ty + i) * 1024 + (bx + tx)];
    __syncthreads();
    #pragma unroll
    for (int i = 0; i < 32; i += 8)
        out[(size_t)(bx + ty + i) * 1024 + (by + tx)] = (_Float16)t[tx][ty + i];
}

// row softmax: S f32 [by][2048][2048] -> f16 rows at dst + by*batStr + row*rowStr
__global__ __launch_bounds__(256) void softmax_k(
    const float* __restrict__ S, _Float16* __restrict__ dst,
    long long rowStr, long long batStr)
{
    const int tid = threadIdx.x;
    const float* row = S + (size_t)blockIdx.y * LN * LN + (size_t)blockIdx.x * LN;
    _Float16* orow = dst + (size_t)blockIdx.y * batStr + (size_t)blockIdx.x * rowStr;

    float4 v0 = *(const float4*)&row[tid * 4];
    float4 v1 = *(const float4*)&row[1024 + tid * 4];

    float m = fmaxf(fmaxf(fmaxf(v0.x, v0.y), fmaxf(v0.z, v0.w)),
                    fmaxf(fmaxf(v1.x, v1.y), fmaxf(v1.z, v1.w)));
    #pragma unroll
    for (int off = 32; off > 0; off >>= 1) m = fmaxf(m, __shfl_xor(m, off));

    __shared__ float red[8];
    if ((tid & 63) == 0) red[tid >> 6] = m;
    __syncthreads();
    m = fmaxf(fmaxf(red[0], red[1]), fmaxf(red[2], red[3]));

    float e[8];
    e[0] = __expf(v0.x - m); e[1] = __expf(v0.y - m);
    e[2] = __expf(v0.z - m); e[3] = __expf(v0.w - m);
    e[4] = __expf(v1.x - m); e[5] = __expf(v1.y - m);
    e[6] = __expf(v1.z - m); e[7] = __expf(v1.w - m);
    float s = ((e[0] + e[1]) + (e[2] + e[3])) + ((e[4] + e[5]) + (e[6] + e[7]));
    #pragma unroll
    for (int off = 32; off > 0; off >>= 1) s += __shfl_xor(s, off);
    if ((tid & 63) == 0) red[4 + (tid >> 6)] = s;
    __syncthreads();
    s = (red[4] + red[5]) + (red[6] + red[7]);

    const float inv = 1.0f / s;
    union { _Float16 h[4]; short4 s4; } a, b;
    a.h[0] = (_Float16)(e[0] * inv); a.h[1] = (_Float16)(e[1] * inv);
    a.h[2] = (_Float16)(e[2] * inv); a.h[3] = (_Float16)(e[3] * inv);
    b.h[0] = (_Float16)(e[4] * inv); b.h[1] = (_Float16)(e[5] * inv);
    b.h[2] = (_Float16)(e[6] * inv); b.h[3] = (_Float16)(e[7] * inv);
    *(short4*)&orow[tid * 4] = a.s4;
    *(short4*)&orow[1024 + tid * 4] = b.s4;
}

// ---------------------------------------------------------------------------
extern "C" void kernel_launch(void* const* d_in, const int* in_sizes, int n_in,
                              void* d_out, int out_size, void* d_ws, size_t ws_size,
                              hipStream_t stream)
{
    (void)in_sizes; (void)n_in; (void)out_size;
    const float* i_in  = (const float*)d_in[0];
    const float* k_w   = (const float*)d_in[1];
    const float* q_w   = (const float*)d_in[2];
    const float* v_w   = (const float*)d_in[3];
    const float* mlp_w = (const float*)d_in[4];
    const float* bias  = (const float*)d_in[5];
    float* out = (float*)d_out;

    (void)hipFuncSetAttribute((const void*)gemm256<2>, hipFuncAttributeMaxDynamicSharedMemorySize, 131072);
    (void)hipFuncSetAttribute((const void*)gemm256<3>, hipFuncAttributeMaxDynamicSharedMemorySize, 131072);
    (void)hipFuncSetAttribute((const void*)gemm256<4>, hipFuncAttributeMaxDynamicSharedMemorySize, 131072);
    (void)hipFuncSetAttribute((const void*)gemm256<5>, hipFuncAttributeMaxDynamicSharedMemorySize, 131072);
    (void)hipFuncSetAttribute((const void*)gemm256<6>, hipFuncAttributeMaxDynamicSharedMemorySize, 131072);

    char* ws = (char*)d_ws;
    const dim3 blk512(512);
    const dim3 blk256(256);
    const dim3 tgrid(32, 32);
    const size_t LDSB = 131072;

    const size_t MiB = 1ull << 20;
    const long long L2048 = 2048, L1024 = 1024, L4096 = 4096;

    if (ws_size >= 236 * MiB) {
        _Float16* Qcat  = (_Float16*)(ws);
        _Float16* Kcat  = (_Float16*)(ws + 64 * MiB);
        _Float16* VT    = (_Float16*)(ws + 128 * MiB);
        _Float16* qCatT = (_Float16*)(ws + 160 * MiB);   // contiguous with kCatT
        _Float16* kCatT = (_Float16*)(ws + 164 * MiB);
        _Float16* vT    = (_Float16*)(ws + 168 * MiB);
        _Float16* mlpT  = (_Float16*)(ws + 170 * MiB);
        _Float16* iCat  = (_Float16*)(ws + 172 * MiB);
        float*    sc    = (float*)(ws + 172 * MiB);     // 4 batches x 16 MiB (aliases iCat)
        _Float16* attA  = Kcat;                          // att[b][2048][2048] f16 = 64 MiB,
                                                         // written per-chunk AFTER scores read Kcat[b]
        _Float16* ret   = Qcat;                          // [16384][1024], dead after scores

        split_i_k<<<dim3(16384), blk256, 0, stream>>>(i_in, iCat, (long long)NB * LN * IDM / 4);
        split_wT_k<<<tgrid, blk256, 0, stream>>>(q_w, qCatT);
        split_wT_k<<<tgrid, blk256, 0, stream>>>(k_w, kCatT);
        transp_f32_f16<<<tgrid, blk256, 0, stream>>>(v_w, vT);
        transp_f32_f16<<<tgrid, blk256, 0, stream>>>(mlp_w, mlpT);

        // fused Q+K projection: B rows 0-1023 = q weight, 1024-2047 = k weight
        gemm256<6><<<dim3(8, 64), blk512, LDSB, stream>>>(
            iCat, L2048, 1024, qCatT + 1024, L2048,
            iCat, L2048, 2048, qCatT, L2048,
            Kcat, Qcat, NB * LN, 2048, 0, 0, 0, 0);
        gemm256<3><<<dim3(4, 64), blk512, LDSB, stream>>>(
            iCat, L2048, 1024, vT, L1024,
            nullptr, 0, 0, nullptr, 0,
            nullptr, VT, NB * LN, 1024, 0, 0, 0, 0);
        // iCat now dead; sc aliases it.

        for (int c = 0; c < 2; ++c) {
            const size_t coff = (size_t)c * 4 * LN * 2048;
            gemm256<2><<<dim3(8, 8, 4), blk512, LDSB, stream>>>(
                Qcat + coff, L2048, 1024, Kcat + coff + 1024, L2048,
                Qcat + coff, L2048, 2048, Kcat + coff, L2048,
                nullptr, sc, LN, LN,
                (long long)LN * 2048, (long long)LN * 2048, (long long)LN * LN, 0);
            // compact att into Kcat region of the SAME batches (just fully read)
            softmax_k<<<dim3(LN, 4), blk256, 0, stream>>>(
                sc, attA + (size_t)c * 4 * LN * LN, L2048, (long long)LN * LN);
        }
        // PV for all 8 batches in ONE dispatch: grid (4,8,8)=256 blocks, full device
        gemm256<4><<<dim3(4, 8, 8), blk512, LDSB, stream>>>(
            attA, L2048, 2048, VT, L2048,
            nullptr, 0, 0, nullptr, 0,
            i_in, ret, LN, IDM,
            (long long)LN * LN, (long long)IDM * LN, (long long)LN * IDM, (long long)LN * IDM);
        gemm256<5><<<dim3(4, 64), blk512, LDSB, stream>>>(
            ret, L1024, 1024, mlpT, L1024,
            nullptr, 0, 0, nullptr, 0,
            bias, out, NB * LN, 1024, 0, 0, 0, 0);
    } else {
        // -------- small path (~60 MiB), per batch --------
        _Float16* qCatT = (_Float16*)(ws);               // contiguous with kCatT
        _Float16* kCatT = (_Float16*)(ws + 4 * MiB);
        _Float16* vT    = (_Float16*)(ws + 8 * MiB);
        _Float16* mlpT  = (_Float16*)(ws + 10 * MiB);
        _Float16* iCat  = (_Float16*)(ws + 12 * MiB);
        _Float16* Qcat  = (_Float16*)(ws + 20 * MiB);
        _Float16* Kcat  = (_Float16*)(ws + 28 * MiB);
        _Float16* VTb   = (_Float16*)(ws + 36 * MiB);
        float*    sc    = (float*)(ws + 40 * MiB);
        _Float16* ret   = (_Float16*)(ws + 56 * MiB);

        split_wT_k<<<tgrid, blk256, 0, stream>>>(q_w, qCatT);
        split_wT_k<<<tgrid, blk256, 0, stream>>>(k_w, kCatT);
        transp_f32_f16<<<tgrid, blk256, 0, stream>>>(v_w, vT);
        transp_f32_f16<<<tgrid, blk256, 0, stream>>>(mlp_w, mlpT);

        for (int b = 0; b < NB; ++b) {
            const size_t boff = (size_t)b * LN * IDM;
            split_i_k<<<dim3(2048), blk256, 0, stream>>>(i_in + boff, iCat, (long long)LN * IDM / 4);
            gemm256<6><<<dim3(8, 8), blk512, LDSB, stream>>>(
                iCat, L2048, 1024, qCatT + 1024, L2048,
                iCat, L2048, 2048, qCatT, L2048,
                Kcat, Qcat, LN, 2048, 0, 0, 0, 0);
            gemm256<3><<<dim3(4, 8), blk512, LDSB, stream>>>(
                iCat, L2048, 1024, vT, L1024,
                nullptr, 0, 0, nullptr, 0,
                nullptr, VTb, LN, 1024, 0, 0, 0, 0);
            gemm256<2><<<dim3(8, 8), blk512, LDSB, stream>>>(
                Qcat, L2048, 1024, Kcat + 1024, L2048,
                Qcat, L2048, 2048, Kcat, L2048,
                nullptr, sc, LN, LN, 0, 0, 0, 0);
            softmax_k<<<dim3(LN, 1), blk256, 0, stream>>>(
                sc, (_Float16*)sc, L4096, 0);   // in-place, f16 rows at stride 4096
            gemm256<4><<<dim3(4, 8), blk512, LDSB, stream>>>(
                (const _Float16*)sc, L4096, 2048, VTb, L2048,
                nullptr, 0, 0, nullptr, 0,
                i_in + boff, ret, LN, IDM, 0, 0, 0, 0);
            gemm256<5><<<dim3(4, 8), blk512, LDSB, stream>>>(
                ret, L1024, 1024, mlpT, L1024,
                nullptr, 0, 0, nullptr, 0,
                bias, out + boff, LN, 1024, 0, 0, 0, 0);
        }
    }
}

// Round 10
// 610.787 us; speedup vs baseline: 2.4121x; 1.0601x over previous
//
#include <hip/hip_runtime.h>
#include <hip/hip_bf16.h>
#include <math.h>

#define LN   2048
#define IDM  1024
#define NB   8
#define NEG_SLOPE 0.2f
#define LO_SCALE   4096.0f      // 2^12: keeps lo parts out of f16 denormal range
#define LO_INV     (1.0f/4096.0f)

typedef _Float16 f16x8 __attribute__((ext_vector_type(8)));
typedef float    f32x4 __attribute__((ext_vector_type(4)));

#define GLDS16(g, l) \
    __builtin_amdgcn_global_load_lds((const __attribute__((address_space(1))) void*)(g), \
                                     (__attribute__((address_space(3))) void*)(l), 16, 0, 0)

extern __shared__ char smem[];   // 128 KiB: 2 step-buffers x (A 32K + B 32K)

// ---------------------------------------------------------------------------
// 256x256 tile, BK=64, 8 waves (2M x 4N), ONE barrier per K-step.
// Per step (per wave): stage A | read aF(16)+bF0(4) | lgkm | stage B, issue
// bF1(4) | 32 MFMA on bF0 (covers bF1 latency) | lgkm | 32 MFMA on bF1.
// No intra-step barriers: regions read the same landed buffer (the step-entry
// barrier alone covers the double-buffer write-after-read hazard), so waves
// desync and one wave's ds_reads overlap other waves' MFMA clusters
// (LDS-BW and matrix pipes run concurrently instead of alternating).
// LDS slot-swizzle key (row>>1)&3, inverse-applied on the global source
// (zero-conflict, verified round 7).
// 2-segment K: (A2,B2,K2) correction first, then acc *= 2^-12, then (A1,B1,K1).
// A: [M][K] f16 rows (stride lda).  B: [N][K] f16 rows (stride ldb).
// EPI: 0 = split store hi|lo  (C f16 [M][2N]) ; 1 = split store lo|hi
//      2 = f32 store [M][N]
//      3 = f16 transposed per-2048-row-batch store: VT[b][N][2048]
//      4 = f16 store of (acc + E_f32[M][N])
//      5 = f32 store of leaky_relu(acc) + E_f32[row&2047][N]
//      6 = fused QK-proj store (N=2048): col<1024 -> Cv=Qcat hi|lo,
//          col>=1024 -> extraV=Kcat lo|hi (both [M][2048])
// ---------------------------------------------------------------------------
template<int EPI>
__global__ __launch_bounds__(512, 2) void gemm256(
    const _Float16* __restrict__ A1, long long lda1, int K1,
    const _Float16* __restrict__ B1, long long ldb1,
    const _Float16* __restrict__ A2, long long lda2, int K2,
    const _Float16* __restrict__ B2, long long ldb2,
    const void* __restrict__ extraV, void* __restrict__ Cv,
    int M, int N,
    long long zsA, long long zsB, long long zsC, long long zsE)
{
    const int tid  = threadIdx.x;

    // bijective XCD swizzle (all launch grids have nwg % 8 == 0)
    const unsigned nx = gridDim.x, ny = gridDim.y;
    const unsigned lid = blockIdx.x + nx * (blockIdx.y + ny * blockIdx.z);
    const unsigned cpx = (nx * ny * gridDim.z) >> 3;
    const unsigned swzid = (lid & 7) * cpx + (lid >> 3);
    const unsigned bx = swzid % nx, rest = swzid / nx;
    const unsigned by = rest % ny;
    const int z  = (int)(rest / ny);
    const int m0 = (int)by * 256, n0 = (int)bx * 256;

    const int lane = tid & 63;
    const int wid  = tid >> 6;
    const int wm   = wid >> 2;        // 0..1  (M half)
    const int wn   = wid & 3;         // 0..3  (N quarter)

    // staging: dest row = tid>>2 (0..127), dest slot = tid&3 (linear dest);
    // source col inverse-swizzled with key (destrow>>1)&3 = (tid>>3)&3
    const int sx   = ((tid & 3) ^ ((tid >> 3) & 3)) << 3;   // f16 units

    const int NT2 = K2 >> 6;
    const int NT  = NT2 + (K1 >> 6);

    const _Float16* A1z = A1 + (size_t)z * zsA;
    const _Float16* B1z = B1 + (size_t)z * zsB;
    const _Float16* A2z = (K2 > 0) ? A2 + (size_t)z * zsA : A1z;
    const _Float16* B2z = (K2 > 0) ? B2 + (size_t)z * zsB : B1z;

    // stage one 128-row half-tile (2 slabs of 32 k) of step st.
    // hh: 0 = A rows 0-127, 1 = A rows 128-255, 2 = B rows 0-127, 3 = B rows 128-255
    auto stageH = [&](int st, int hh) {
        if (st >= NT) return;
        const _Float16* P; long long ld; int kk;
        if (st < NT2) { P = (hh < 2) ? A2z : B2z; ld = (hh < 2) ? lda2 : ldb2; kk = st << 6; }
        else          { P = (hh < 2) ? A1z : B1z; ld = (hh < 2) ? lda1 : ldb1; kk = (st - NT2) << 6; }
        const int row0 = ((hh < 2) ? m0 : n0) + (hh & 1) * 128 + (tid >> 2);
        char* dst = smem + (size_t)(st & 1) * 65536 + ((hh >= 2) ? 32768 : 0)
                         + (hh & 1) * 16384 + tid * 16;
        const _Float16* src = P + (size_t)row0 * ld + kk + sx;
        GLDS16(src, dst);              // slab 0 (k 0-31)
        GLDS16(src + 32, dst + 8192);  // slab 1 (k 32-63)
    };

    const int fr   = lane & 15;
    const int ks4  = (((lane >> 4) ^ ((lane >> 1) & 3)) << 4);  // swizzled byte slot
    const int brow = (wn & 1) * 64 + fr;                        // B row base within half

    f32x4 acc[8][4] = {};
    f16x8 aF[2][4][2];       // both m-halves cached (64 VGPR)
    f16x8 bF0[2][2];         // B quadrant 0 (16 VGPR)
    f16x8 bF1[2][2];         // B quadrant 1 (16 VGPR)

    auto readA2 = [&](const char* bufA) {
        #pragma unroll
        for (int mh = 0; mh < 2; ++mh)
            #pragma unroll
            for (int mf = 0; mf < 4; ++mf)
                #pragma unroll
                for (int sl = 0; sl < 2; ++sl)
                    aF[mh][mf][sl] = *(const f16x8*)(bufA + sl * 8192 + ((mh * 4 + mf) * 16 + fr) * 64 + ks4);
    };
    auto readB0 = [&](const char* bufB) {
        #pragma unroll
        for (int nf = 0; nf < 2; ++nf)
            #pragma unroll
            for (int sl = 0; sl < 2; ++sl)
                bF0[nf][sl] = *(const f16x8*)(bufB + sl * 8192 + (brow + nf * 16) * 64 + ks4);
    };
    auto readB1 = [&](const char* bufB) {
        #pragma unroll
        for (int nf = 0; nf < 2; ++nf)
            #pragma unroll
            for (int sl = 0; sl < 2; ++sl)
                bF1[nf][sl] = *(const f16x8*)(bufB + sl * 8192 + (brow + (2 + nf) * 16) * 64 + ks4);
    };
    auto mmaN = [&](int nh) {   // nh=0 uses bF0 -> acc[.][0..1]; nh=1 uses bF1 -> acc[.][2..3]
        __builtin_amdgcn_s_setprio(1);
        #pragma unroll
        for (int mh = 0; mh < 2; ++mh)
            #pragma unroll
            for (int mf = 0; mf < 4; ++mf)
                #pragma unroll
                for (int nf = 0; nf < 2; ++nf)
                    #pragma unroll
                    for (int sl = 0; sl < 2; ++sl)
                        acc[mh * 4 + mf][nh * 2 + nf] = __builtin_amdgcn_mfma_f32_16x16x32_f16(
                            aF[mh][mf][sl], (nh == 0) ? bF0[nf][sl] : bF1[nf][sl],
                            acc[mh * 4 + mf][nh * 2 + nf], 0, 0, 0);
        __builtin_amdgcn_s_setprio(0);
    };

    // prologue: stage step 0
    stageH(0, 0); stageH(0, 1); stageH(0, 2); stageH(0, 3);

    #pragma unroll 1
    for (int s = 0; s < NT; ++s) {
        const char* base = smem + (size_t)(s & 1) * 65536;
        const char* bufA = base + wm * 16384;
        const char* bufB = base + 32768 + (wn >> 1) * 16384;

        asm volatile("s_waitcnt vmcnt(0)" ::: "memory");   // step s fully landed
        __builtin_amdgcn_s_barrier();                      // the ONLY barrier per step
        __builtin_amdgcn_sched_barrier(0);

        stageH(s + 1, 0); stageH(s + 1, 1);
        readA2(bufA); readB0(bufB);                        // 20 ds_reads
        asm volatile("s_waitcnt lgkmcnt(0)" ::: "memory");
        __builtin_amdgcn_sched_barrier(0);

        stageH(s + 1, 2); stageH(s + 1, 3);
        readB1(bufB);                                      // latency hides under mmaN(0)
        mmaN(0);                                           // 32 MFMA on bF0
        asm volatile("s_waitcnt lgkmcnt(0)" ::: "memory");
        __builtin_amdgcn_sched_barrier(0);
        mmaN(1);                                           // 32 MFMA on bF1

        if (s == NT2 - 1) {
            #pragma unroll
            for (int mf = 0; mf < 8; ++mf)
                #pragma unroll
                for (int nf = 0; nf < 4; ++nf)
                    acc[mf][nf] *= LO_INV;
        }
    }

    // C/D layout: col = lane&15, row = (lane>>4)*4 + reg
    const int colb = n0 + wn * 64 + (lane & 15);
    const int rowb = m0 + wm * 128 + ((lane >> 4) << 2);

    if (EPI == 0 || EPI == 1) {
        _Float16* C = (_Float16*)Cv + (size_t)z * zsC;
        const long long ldc = 2 * (long long)N;
        #pragma unroll
        for (int mf = 0; mf < 8; ++mf)
            #pragma unroll
            for (int nf = 0; nf < 4; ++nf)
                #pragma unroll
                for (int r = 0; r < 4; ++r) {
                    const int row = rowb + mf * 16 + r;
                    const int col = colb + nf * 16;
                    float v = acc[mf][nf][r];
                    _Float16 h = (_Float16)v;
                    _Float16 l = (_Float16)((v - (float)h) * LO_SCALE);
                    if (EPI == 0) {
                        C[(size_t)row * ldc + col]     = h;
                        C[(size_t)row * ldc + N + col] = l;
                    } else {
                        C[(size_t)row * ldc + col]     = l;
                        C[(size_t)row * ldc + N + col] = h;
                    }
                }
    } else if (EPI == 2) {
        float* C = (float*)Cv + (size_t)z * zsC;
        #pragma unroll
        for (int mf = 0; mf < 8; ++mf)
            #pragma unroll
            for (int nf = 0; nf < 4; ++nf)
                #pragma unroll
                for (int r = 0; r < 4; ++r)
                    C[(size_t)(rowb + mf * 16 + r) * N + (colb + nf * 16)] = acc[mf][nf][r];
    } else if (EPI == 3) {
        _Float16* C = (_Float16*)Cv;   // VT: [batch][N][2048]
        #pragma unroll
        for (int mf = 0; mf < 8; ++mf) {
            const int row = rowb + mf * 16;
            const int bt = row >> 11, ml = row & 2047;
            #pragma unroll
            for (int nf = 0; nf < 4; ++nf) {
                union { _Float16 h[4]; short4 s4; } u;
                #pragma unroll
                for (int r = 0; r < 4; ++r) u.h[r] = (_Float16)acc[mf][nf][r];
                *(short4*)&C[(size_t)bt * (size_t)IDM * 2048 + (size_t)(colb + nf * 16) * 2048 + ml] = u.s4;
            }
        }
    } else if (EPI == 4) {
        _Float16* C = (_Float16*)Cv + (size_t)z * zsC;
        const float* E = (const float*)extraV + (size_t)z * zsE;
        #pragma unroll
        for (int mf = 0; mf < 8; ++mf)
            #pragma unroll
            for (int nf = 0; nf < 4; ++nf)
                #pragma unroll
                for (int r = 0; r < 4; ++r) {
                    const size_t idx = (size_t)(rowb + mf * 16 + r) * N + (colb + nf * 16);
                    C[idx] = (_Float16)(acc[mf][nf][r] + E[idx]);
                }
    } else if (EPI == 5) {
        float* C = (float*)Cv;
        const float* E = (const float*)extraV;
        #pragma unroll
        for (int mf = 0; mf < 8; ++mf)
            #pragma unroll
            for (int nf = 0; nf < 4; ++nf)
                #pragma unroll
                for (int r = 0; r < 4; ++r) {
                    const int row = rowb + mf * 16 + r;
                    const int col = colb + nf * 16;
                    float v = acc[mf][nf][r];
                    v = (v >= 0.f) ? v : NEG_SLOPE * v;
                    C[(size_t)row * N + col] = v + E[(size_t)(row & (LN - 1)) * N + col];
                }
    } else {  // EPI == 6: fused QK projection store
        _Float16* Cq = (_Float16*)Cv;                       // Qcat [M][2048] hi|lo
        _Float16* Ck = (_Float16*)const_cast<void*>(extraV);// Kcat [M][2048] lo|hi
        #pragma unroll
        for (int mf = 0; mf < 8; ++mf)
            #pragma unroll
            for (int nf = 0; nf < 4; ++nf)
                #pragma unroll
                for (int r = 0; r < 4; ++r) {
                    const int row = rowb + mf * 16 + r;
                    const int col = colb + nf * 16;        // 0..2047
                    float v = acc[mf][nf][r];
                    _Float16 h = (_Float16)v;
                    _Float16 l = (_Float16)((v - (float)h) * LO_SCALE);
                    if (col < 1024) {
                        Cq[(size_t)row * 2048 + col]        = h;
                        Cq[(size_t)row * 2048 + 1024 + col] = l;
                    } else {
                        Ck[(size_t)row * 2048 + col]        = h;
                        Ck[(size_t)row * 2048 + col - 1024] = l;
                    }
                }
    }
}

// ---------------------------------------------------------------------------
// i split: f32 [M][1024] -> f16 [M][2048]  (hi | lo*2^12)
__global__ __launch_bounds__(256) void split_i_k(
    const float* __restrict__ in, _Float16* __restrict__ out, long long n4)
{
    long long idx = (long long)blockIdx.x * 256 + threadIdx.x;
    if (idx >= n4) return;
    float4 v = ((const float4*)in)[idx];
    long long row = idx >> 8;
    int c4 = (int)(idx & 255) * 4;
    union { _Float16 h[4]; short4 s4; } hi, lo;
    float f0 = v.x; _Float16 h0 = (_Float16)f0; hi.h[0] = h0; lo.h[0] = (_Float16)((f0 - (float)h0) * LO_SCALE);
    float f1 = v.y; _Float16 h1 = (_Float16)f1; hi.h[1] = h1; lo.h[1] = (_Float16)((f1 - (float)h1) * LO_SCALE);
    float f2 = v.z; _Float16 h2 = (_Float16)f2; hi.h[2] = h2; lo.h[2] = (_Float16)((f2 - (float)h2) * LO_SCALE);
    float f3 = v.w; _Float16 h3 = (_Float16)f3; hi.h[3] = h3; lo.h[3] = (_Float16)((f3 - (float)h3) * LO_SCALE);
    *(short4*)&out[row * 2048 + c4]        = hi.s4;
    *(short4*)&out[row * 2048 + 1024 + c4] = lo.s4;
}

// weight transpose+split: in [K=1024][N=1024] f32 -> out [N][2048] (lo*2^12 | hi)
__global__ __launch_bounds__(256) void split_wT_k(
    const float* __restrict__ in, _Float16* __restrict__ out)
{
    __shared__ float t[32][33];
    const int bx = blockIdx.x * 32, by = blockIdx.y * 32;
    const int tx = threadIdx.x & 31, ty = threadIdx.x >> 5;
    #pragma unroll
    for (int i = 0; i < 32; i += 8)
        t[ty + i][tx] = in[(size_t)(by + ty + i) * 1024 + (bx + tx)];
    __syncthreads();
    #pragma unroll
    for (int i = 0; i < 32; i += 8) {
        float f = t[tx][ty + i];
        _Float16 h = (_Float16)f;
        _Float16 l = (_Float16)((f - (float)h) * LO_SCALE);
        const size_t n = bx + ty + i, k = by + tx;
        out[n * 2048 + k]        = l;
        out[n * 2048 + 1024 + k] = h;
    }
}

// plain transpose+convert: in [K=1024][N=1024] f32 -> out [N][1024] f16
__global__ __launch_bounds__(256) void transp_f32_f16(
    const float* __restrict__ in, _Float16* __restrict__ out)
{
    __shared__ float t[32][33];
    const int bx = blockIdx.x * 32, by = blockIdx.y * 32;
    const int tx = threadIdx.x & 31, ty = threadIdx.x >> 5;
    #pragma unroll
    for (int i = 0; i < 32; i += 8)
        t[ty + i][tx] = in[(size_t)(by + ty + i) * 1024 + (bx + tx)];
    __syncthreads();
    #pragma unroll
    for (int i = 0; i < 32; i += 8)
        out[(size_t)(bx + ty + i) * 1024 + (by + tx)] = (_Float16)t[tx][ty + i];
}

// row softmax: S f32 [by][2048][2048] -> f16 rows at dst + by*batStr + row*rowStr
__global__ __launch_bounds__(256) void softmax_k(
    const float* __restrict__ S, _Float16* __restrict__ dst,
    long long rowStr, long long batStr)
{
    const int tid = threadIdx.x;
    const float* row = S + (size_t)blockIdx.y * LN * LN + (size_t)blockIdx.x * LN;
    _Float16* orow = dst + (size_t)blockIdx.y * batStr + (size_t)blockIdx.x * rowStr;

    float4 v0 = *(const float4*)&row[tid * 4];
    float4 v1 = *(const float4*)&row[1024 + tid * 4];

    float m = fmaxf(fmaxf(fmaxf(v0.x, v0.y), fmaxf(v0.z, v0.w)),
                    fmaxf(fmaxf(v1.x, v1.y), fmaxf(v1.z, v1.w)));
    #pragma unroll
    for (int off = 32; off > 0; off >>= 1) m = fmaxf(m, __shfl_xor(m, off));

    __shared__ float red[8];
    if ((tid & 63) == 0) red[tid >> 6] = m;
    __syncthreads();
    m = fmaxf(fmaxf(red[0], red[1]), fmaxf(red[2], red[3]));

    float e[8];
    e[0] = __expf(v0.x - m); e[1] = __expf(v0.y - m);
    e[2] = __expf(v0.z - m); e[3] = __expf(v0.w - m);
    e[4] = __expf(v1.x - m); e[5] = __expf(v1.y - m);
    e[6] = __expf(v1.z - m); e[7] = __expf(v1.w - m);
    float s = ((e[0] + e[1]) + (e[2] + e[3])) + ((e[4] + e[5]) + (e[6] + e[7]));
    #pragma unroll
    for (int off = 32; off > 0; off >>= 1) s += __shfl_xor(s, off);
    if ((tid & 63) == 0) red[4 + (tid >> 6)] = s;
    __syncthreads();
    s = (red[4] + red[5]) + (red[6] + red[7]);

    const float inv = 1.0f / s;
    union { _Float16 h[4]; short4 s4; } a, b;
    a.h[0] = (_Float16)(e[0] * inv); a.h[1] = (_Float16)(e[1] * inv);
    a.h[2] = (_Float16)(e[2] * inv); a.h[3] = (_Float16)(e[3] * inv);
    b.h[0] = (_Float16)(e[4] * inv); b.h[1] = (_Float16)(e[5] * inv);
    b.h[2] = (_Float16)(e[6] * inv); b.h[3] = (_Float16)(e[7] * inv);
    *(short4*)&orow[tid * 4] = a.s4;
    *(short4*)&orow[1024 + tid * 4] = b.s4;
}

// ---------------------------------------------------------------------------
extern "C" void kernel_launch(void* const* d_in, const int* in_sizes, int n_in,
                              void* d_out, int out_size, void* d_ws, size_t ws_size,
                              hipStream_t stream)
{
    (void)in_sizes; (void)n_in; (void)out_size;
    const float* i_in  = (const float*)d_in[0];
    const float* k_w   = (const float*)d_in[1];
    const float* q_w   = (const float*)d_in[2];
    const float* v_w   = (const float*)d_in[3];
    const float* mlp_w = (const float*)d_in[4];
    const float* bias  = (const float*)d_in[5];
    float* out = (float*)d_out;

    (void)hipFuncSetAttribute((const void*)gemm256<2>, hipFuncAttributeMaxDynamicSharedMemorySize, 131072);
    (void)hipFuncSetAttribute((const void*)gemm256<3>, hipFuncAttributeMaxDynamicSharedMemorySize, 131072);
    (void)hipFuncSetAttribute((const void*)gemm256<4>, hipFuncAttributeMaxDynamicSharedMemorySize, 131072);
    (void)hipFuncSetAttribute((const void*)gemm256<5>, hipFuncAttributeMaxDynamicSharedMemorySize, 131072);
    (void)hipFuncSetAttribute((const void*)gemm256<6>, hipFuncAttributeMaxDynamicSharedMemorySize, 131072);

    char* ws = (char*)d_ws;
    const dim3 blk512(512);
    const dim3 blk256(256);
    const dim3 tgrid(32, 32);
    const size_t LDSB = 131072;

    const size_t MiB = 1ull << 20;
    const long long L2048 = 2048, L1024 = 1024, L4096 = 4096;

    if (ws_size >= 236 * MiB) {
        _Float16* Qcat  = (_Float16*)(ws);
        _Float16* Kcat  = (_Float16*)(ws + 64 * MiB);
        _Float16* VT    = (_Float16*)(ws + 128 * MiB);
        _Float16* qCatT = (_Float16*)(ws + 160 * MiB);   // contiguous with kCatT
        _Float16* kCatT = (_Float16*)(ws + 164 * MiB);
        _Float16* vT    = (_Float16*)(ws + 168 * MiB);
        _Float16* mlpT  = (_Float16*)(ws + 170 * MiB);
        _Float16* iCat  = (_Float16*)(ws + 172 * MiB);
        float*    sc    = (float*)(ws + 172 * MiB);     // 4 batches x 16 MiB (aliases iCat)
        _Float16* attA  = Kcat;                          // att[b][2048][2048] f16 = 64 MiB,
                                                         // written per-chunk AFTER scores read Kcat[b]
        _Float16* ret   = Qcat;                          // [16384][1024], dead after scores

        split_i_k<<<dim3(16384), blk256, 0, stream>>>(i_in, iCat, (long long)NB * LN * IDM / 4);
        split_wT_k<<<tgrid, blk256, 0, stream>>>(q_w, qCatT);
        split_wT_k<<<tgrid, blk256, 0, stream>>>(k_w, kCatT);
        transp_f32_f16<<<tgrid, blk256, 0, stream>>>(v_w, vT);
        transp_f32_f16<<<tgrid, blk256, 0, stream>>>(mlp_w, mlpT);

        // fused Q+K projection: B rows 0-1023 = q weight, 1024-2047 = k weight
        gemm256<6><<<dim3(8, 64), blk512, LDSB, stream>>>(
            iCat, L2048, 1024, qCatT + 1024, L2048,
            iCat, L2048, 2048, qCatT, L2048,
            Kcat, Qcat, NB * LN, 2048, 0, 0, 0, 0);
        gemm256<3><<<dim3(4, 64), blk512, LDSB, stream>>>(
            iCat, L2048, 1024, vT, L1024,
            nullptr, 0, 0, nullptr, 0,
            nullptr, VT, NB * LN, 1024, 0, 0, 0, 0);
        // iCat now dead; sc aliases it.

        for (int c = 0; c < 2; ++c) {
            const size_t coff = (size_t)c * 4 * LN * 2048;
            gemm256<2><<<dim3(8, 8, 4), blk512, LDSB, stream>>>(
                Qcat + coff, L2048, 1024, Kcat + coff + 1024, L2048,
                Qcat + coff, L2048, 2048, Kcat + coff, L2048,
                nullptr, sc, LN, LN,
                (long long)LN * 2048, (long long)LN * 2048, (long long)LN * LN, 0);
            // compact att into Kcat region of the SAME batches (just fully read)
            softmax_k<<<dim3(LN, 4), blk256, 0, stream>>>(
                sc, attA + (size_t)c * 4 * LN * LN, L2048, (long long)LN * LN);
        }
        // PV for all 8 batches in ONE dispatch: grid (4,8,8)=256 blocks, full device
        gemm256<4><<<dim3(4, 8, 8), blk512, LDSB, stream>>>(
            attA, L2048, 2048, VT, L2048,
            nullptr, 0, 0, nullptr, 0,
            i_in, ret, LN, IDM,
            (long long)LN * LN, (long long)IDM * LN, (long long)LN * IDM, (long long)LN * IDM);
        gemm256<5><<<dim3(4, 64), blk512, LDSB, stream>>>(
            ret, L1024, 1024, mlpT, L1024,
            nullptr, 0, 0, nullptr, 0,
            bias, out, NB * LN, 1024, 0, 0, 0, 0);
    } else {
        // -------- small path (~60 MiB), per batch --------
        _Float16* qCatT = (_Float16*)(ws);               // contiguous with kCatT
        _Float16* kCatT = (_Float16*)(ws + 4 * MiB);
        _Float16* vT    = (_Float16*)(ws + 8 * MiB);
        _Float16* mlpT  = (_Float16*)(ws + 10 * MiB);
        _Float16* iCat  = (_Float16*)(ws + 12 * MiB);
        _Float16* Qcat  = (_Float16*)(ws + 20 * MiB);
        _Float16* Kcat  = (_Float16*)(ws + 28 * MiB);
        _Float16* VTb   = (_Float16*)(ws + 36 * MiB);
        float*    sc    = (float*)(ws + 40 * MiB);
        _Float16* ret   = (_Float16*)(ws + 56 * MiB);

        split_wT_k<<<tgrid, blk256, 0, stream>>>(q_w, qCatT);
        split_wT_k<<<tgrid, blk256, 0, stream>>>(k_w, kCatT);
        transp_f32_f16<<<tgrid, blk256, 0, stream>>>(v_w, vT);
        transp_f32_f16<<<tgrid, blk256, 0, stream>>>(mlp_w, mlpT);

        for (int b = 0; b < NB; ++b) {
            const size_t boff = (size_t)b * LN * IDM;
            split_i_k<<<dim3(2048), blk256, 0, stream>>>(i_in + boff, iCat, (long long)LN * IDM / 4);
            gemm256<6><<<dim3(8, 8), blk512, LDSB, stream>>>(
                iCat, L2048, 1024, qCatT + 1024, L2048,
                iCat, L2048, 2048, qCatT, L2048,
                Kcat, Qcat, LN, 2048, 0, 0, 0, 0);
            gemm256<3><<<dim3(4, 8), blk512, LDSB, stream>>>(
                iCat, L2048, 1024, vT, L1024,
                nullptr, 0, 0, nullptr, 0,
                nullptr, VTb, LN, 1024, 0, 0, 0, 0);
            gemm256<2><<<dim3(8, 8), blk512, LDSB, stream>>>(
                Qcat, L2048, 1024, Kcat + 1024, L2048,
                Qcat, L2048, 2048, Kcat, L2048,
                nullptr, sc, LN, LN, 0, 0, 0, 0);
            softmax_k<<<dim3(LN, 1), blk256, 0, stream>>>(
                sc, (_Float16*)sc, L4096, 0);   // in-place, f16 rows at stride 4096
            gemm256<4><<<dim3(4, 8), blk512, LDSB, stream>>>(
                (const _Float16*)sc, L4096, 2048, VTb, L2048,
                nullptr, 0, 0, nullptr, 0,
                i_in + boff, ret, LN, IDM, 0, 0, 0, 0);
            gemm256<5><<<dim3(4, 8), blk512, LDSB, stream>>>(
                ret, L1024, 1024, mlpT, L1024,
                nullptr, 0, 0, nullptr, 0,
                bias, out + boff, LN, 1024, 0, 0, 0, 0);
        }
    }
}